// Round 2
// baseline (1963.843 us; speedup 1.0000x reference)
//
#include <hip/hip_runtime.h>

// GCN fused pipeline for n=100k, E=1.6M, D=64.
// Packing assumes n <= 2^17 (src fits in 17 bits).

#define TPB 256
#define CAP_S2 10240   // LDS staging entries in scatter2 (coarse bucket max ~8.6k)
#define CAP_E 1024     // staged edges per chunk in fused layer

// ---------------- prep ----------------

__global__ void zero_int_kernel(int* __restrict__ p, int n) {
  int i = blockIdx.x * TPB + threadIdx.x;
  if (i < n) p[i] = 0;
}

// out-degree (random atomics) + coarse bucket histogram (LDS-aggregated)
__global__ __launch_bounds__(256) void degree_coarse(
    const int* __restrict__ src, const int* __restrict__ dst, int e,
    int* __restrict__ deg_out, int* __restrict__ c_cnt, int nb2) {
  __shared__ int hist[1024];
  int t = threadIdx.x;
  for (int i = t; i < nb2; i += TPB) hist[i] = 0;
  __syncthreads();
  int base = blockIdx.x * 4096;
  #pragma unroll
  for (int k = 0; k < 16; k++) {
    int i = base + t + k * TPB;
    if (i < e) {
      atomicAdd(&deg_out[src[i]], 1);
      atomicAdd(&hist[dst[i] >> 9], 1);
    }
  }
  __syncthreads();
  for (int i = t; i < nb2; i += TPB) if (hist[i]) atomicAdd(&c_cnt[i], hist[i]);
}

__global__ void invsqrt_kernel(const int* __restrict__ deg, float* __restrict__ inv, int n) {
  int i = blockIdx.x * TPB + threadIdx.x;
  if (i < n) inv[i] = rsqrtf(fmaxf((float)deg[i], 1.0f));
}

// exclusive scan of coarse counts (nb2 <= ~2048), one block
__global__ void scan_coarse(const int* __restrict__ c_cnt, int nb2,
                            int* __restrict__ c_base, int* __restrict__ c_cursor,
                            int* __restrict__ f_base, int nbf, int e) {
  __shared__ int lds[TPB];
  int t = threadIdx.x;
  int ch = (nb2 + TPB - 1) / TPB;
  int lo = t * ch, hi = min(lo + ch, nb2);
  int sum = 0;
  for (int i = lo; i < hi; i++) sum += c_cnt[i];
  lds[t] = sum; __syncthreads();
  for (int off = 1; off < TPB; off <<= 1) {
    int add = (t >= off) ? lds[t - off] : 0;
    __syncthreads();
    lds[t] += add;
    __syncthreads();
  }
  int run = (t == 0) ? 0 : lds[t - 1];
  for (int i = lo; i < hi; i++) { c_base[i] = run; c_cursor[i] = run; run += c_cnt[i]; }
  if (t == 0) { c_base[nb2] = e; f_base[nbf] = e; }
}

// scatter edges into coarse buckets, packed (src<<9)|dst_local9
__global__ __launch_bounds__(256) void scatter1(
    const int* __restrict__ src, const int* __restrict__ dst, int e,
    int* __restrict__ c_cursor, unsigned* __restrict__ edges1, int nb2) {
  __shared__ int hist[1024];
  int t = threadIdx.x;
  for (int i = t; i < nb2; i += TPB) hist[i] = 0;
  __syncthreads();
  int base = blockIdx.x * 4096;
  #pragma unroll
  for (int k = 0; k < 16; k++) {
    int i = base + t + k * TPB;
    if (i < e) atomicAdd(&hist[dst[i] >> 9], 1);
  }
  __syncthreads();
  for (int i = t; i < nb2; i += TPB) {
    int c = hist[i];
    hist[i] = c ? atomicAdd(&c_cursor[i], c) : 0;
  }
  __syncthreads();
  #pragma unroll
  for (int k = 0; k < 16; k++) {
    int i = base + t + k * TPB;
    if (i < e) {
      int d = dst[i];
      int pos = atomicAdd(&hist[d >> 9], 1);
      edges1[pos] = ((unsigned)src[i] << 9) | (unsigned)(d & 511);
    }
  }
}

// within each coarse bucket: counting-sort into 32-row fine buckets via LDS,
// write coalesced, emit fine-bucket boundaries. repack to (src<<5)|dst_local5.
__global__ __launch_bounds__(256) void scatter2(
    const unsigned* __restrict__ edges1, const int* __restrict__ c_base,
    unsigned* __restrict__ edges2, int* __restrict__ f_base, int n, int nb2) {
  __shared__ unsigned sOut[CAP_S2];
  __shared__ int hist[16], cur[16];
  int b = blockIdx.x, t = threadIdx.x;
  int s = c_base[b], e = c_base[b + 1];
  int rstart = b << 9;
  int nsub = min(16, (n - rstart + 31) >> 5);
  if (t < 16) hist[t] = 0;
  __syncthreads();
  for (int i = s + t; i < e; i += TPB) {
    unsigned v = edges1[i];
    atomicAdd(&hist[(v & 511u) >> 5], 1);
  }
  __syncthreads();
  if (t == 0) {
    int acc = 0;
    for (int j = 0; j < nsub; j++) {
      int c = hist[j];
      cur[j] = acc;
      f_base[(b << 4) + j] = s + acc;
      acc += c;
    }
  }
  __syncthreads();
  for (int i = s + t; i < e; i += TPB) {
    unsigned v = edges1[i];
    int bin = (int)((v & 511u) >> 5);
    int pos = atomicAdd(&cur[bin], 1);
    unsigned ev = ((v >> 9) << 5) | (v & 31u);
    if (pos < CAP_S2) sOut[pos] = ev;
    else edges2[s + pos] = ev;   // statistically never; correctness fallback
  }
  __syncthreads();
  int m = min(e - s, CAP_S2);
  for (int k = t; k < m; k += TPB) edges2[s + k] = sOut[k];
}

// ---------------- fused layer: SpMM (LDS accum) + GEMM + bias + ReLU + pool ----------------
// block = one fine bucket of 32 dst rows; 256 threads = 4 waves.
__global__ __launch_bounds__(256) void fused_layer(
    const float* __restrict__ x, int ldx,
    const unsigned* __restrict__ edges2, const int* __restrict__ f_base,
    const float* __restrict__ inv_out,
    const float* __restrict__ W, const float* __restrict__ bias,
    float* __restrict__ out_cat, float* __restrict__ out_pool, int n) {
  __shared__ float sW[4096];
  __shared__ float sAgg[32][68];    // stride 68: conflict-free ds_add + GEMM broadcast
  __shared__ unsigned sEdge[CAP_E];
  __shared__ int sCnt[32];
  __shared__ float sInv[32];
  int t = threadIdx.x, b = blockIdx.x;
  int row0 = b << 5;
  for (int k = t * 4; k < 4096; k += 1024) *(float4*)&sW[k] = *(const float4*)&W[k];
  for (int k = t; k < 32 * 68; k += TPB) ((float*)sAgg)[k] = 0.f;
  if (t < 32) sCnt[t] = 0;
  int s = f_base[b], e = f_base[b + 1];
  int lane = t & 63, wv = t >> 6;

  for (int cs = s; cs < e; cs += CAP_E) {
    int m = min(CAP_E, e - cs);
    __syncthreads();                 // previous chunk fully consumed (also covers init)
    for (int k = t; k < m; k += TPB) sEdge[k] = edges2[cs + k];
    __syncthreads();
    int i = wv;
    for (; i + 12 < m; i += 16) {    // 4 gathers in flight per wave
      unsigned u0 = sEdge[i], u1 = sEdge[i + 4], u2 = sEdge[i + 8], u3 = sEdge[i + 12];
      int s0 = u0 >> 5, s1 = u1 >> 5, s2 = u2 >> 5, s3 = u3 >> 5;
      int r0 = u0 & 31u, r1 = u1 & 31u, r2_ = u2 & 31u, r3 = u3 & 31u;
      float w0 = inv_out[s0], w1 = inv_out[s1], w2 = inv_out[s2], w3 = inv_out[s3];
      float x0 = x[(size_t)s0 * ldx + lane];
      float x1 = x[(size_t)s1 * ldx + lane];
      float x2 = x[(size_t)s2 * ldx + lane];
      float x3 = x[(size_t)s3 * ldx + lane];
      atomicAdd(&sAgg[r0][lane], x0 * w0);
      atomicAdd(&sAgg[r1][lane], x1 * w1);
      atomicAdd(&sAgg[r2_][lane], x2 * w2);
      atomicAdd(&sAgg[r3][lane], x3 * w3);
      if (lane == 0) {
        atomicAdd(&sCnt[r0], 1); atomicAdd(&sCnt[r1], 1);
        atomicAdd(&sCnt[r2_], 1); atomicAdd(&sCnt[r3], 1);
      }
    }
    for (; i < m; i += 4) {
      unsigned u0 = sEdge[i];
      int s0 = u0 >> 5; int r0 = u0 & 31u;
      float w0 = inv_out[s0];
      float x0 = x[(size_t)s0 * ldx + lane];
      atomicAdd(&sAgg[r0][lane], x0 * w0);
      if (lane == 0) atomicAdd(&sCnt[r0], 1);
    }
  }
  __syncthreads();
  if (t < 32) sInv[t] = rsqrtf(fmaxf((float)sCnt[t], 1.0f));
  __syncthreads();

  // GEMM: thread -> cols jj..jj+3, rows rA (even) and rB (odd)
  int jj = (t & 15) << 2;
  int rg = t >> 4;              // 0..15
  int rA = rg << 1, rB = rA + 1;
  float4 aA = {0, 0, 0, 0}, aB = {0, 0, 0, 0};
  #pragma unroll 8
  for (int f = 0; f < 64; f++) {
    float4 w4 = *(const float4*)&sW[(f << 6) + jj];
    float xA = sAgg[rA][f], xB = sAgg[rB][f];
    aA.x = fmaf(xA, w4.x, aA.x); aA.y = fmaf(xA, w4.y, aA.y);
    aA.z = fmaf(xA, w4.z, aA.z); aA.w = fmaf(xA, w4.w, aA.w);
    aB.x = fmaf(xB, w4.x, aB.x); aB.y = fmaf(xB, w4.y, aB.y);
    aB.z = fmaf(xB, w4.z, aB.z); aB.w = fmaf(xB, w4.w, aB.w);
  }
  float4 bv = *(const float4*)&bias[jj];
  float iiA = sInv[rA], iiB = sInv[rB];
  #pragma unroll
  for (int half = 0; half < 2; half++) {
    int row = row0 + (half ? rB : rA);
    float ii = half ? iiB : iiA;
    float4 a = half ? aB : aA;
    if (row < n) {
      float4 h;
      h.x = fmaxf(fmaf(a.x, ii, bv.x), 0.f);
      h.y = fmaxf(fmaf(a.y, ii, bv.y), 0.f);
      h.z = fmaxf(fmaf(a.z, ii, bv.z), 0.f);
      h.w = fmaxf(fmaf(a.w, ii, bv.w), 0.f);
      *(float4*)&out_cat[(size_t)row * 192 + jj] = h;
      float part = h.x + h.y + h.z + h.w;
      part += __shfl_xor(part, 1);
      part += __shfl_xor(part, 2);
      part += __shfl_xor(part, 4);
      part += __shfl_xor(part, 8);
      if ((t & 15) == 0) out_pool[row] = part;
    }
  }
}

// ---------------- launch ----------------

extern "C" void kernel_launch(void* const* d_in, const int* in_sizes, int n_in,
                              void* d_out, int out_size, void* d_ws, size_t ws_size,
                              hipStream_t stream) {
  const float* node_feat = (const float*)d_in[0];
  const int* src = (const int*)d_in[1];
  const int* dst = (const int*)d_in[2];
  const float* Ws[3] = {(const float*)d_in[4], (const float*)d_in[6], (const float*)d_in[8]};
  const float* bs[3] = {(const float*)d_in[5], (const float*)d_in[7], (const float*)d_in[9]};
  float* out = (float*)d_out;
  int n = in_sizes[0] / 64;
  int e = in_sizes[1];
  int nb2 = (n + 511) / 512;        // coarse buckets (512 rows)
  int nbf = (n + 31) / 32;          // fine buckets (32 rows)

  char* p = (char*)d_ws;
  int* deg_out = (int*)p;   p += (size_t)n * sizeof(int);
  int* c_cnt = (int*)p;     p += (size_t)nb2 * sizeof(int);
  int* c_base = (int*)p;    p += (size_t)(nb2 + 1) * sizeof(int);
  int* c_cursor = (int*)p;  p += (size_t)nb2 * sizeof(int);
  int* f_base = (int*)p;    p += (size_t)(nbf + 1) * sizeof(int);
  float* inv_out = (float*)p; p += (size_t)n * sizeof(float);
  unsigned* edges1 = (unsigned*)p; p += (size_t)e * sizeof(unsigned);
  unsigned* edges2 = (unsigned*)p; p += (size_t)e * sizeof(unsigned);

  int eb = (e + 4095) / 4096;

  zero_int_kernel<<<(n + nb2 + TPB - 1) / TPB, TPB, 0, stream>>>(deg_out, n + nb2);
  degree_coarse<<<eb, TPB, 0, stream>>>(src, dst, e, deg_out, c_cnt, nb2);
  scan_coarse<<<1, TPB, 0, stream>>>(c_cnt, nb2, c_base, c_cursor, f_base, nbf, e);
  scatter1<<<eb, TPB, 0, stream>>>(src, dst, e, c_cursor, edges1, nb2);
  scatter2<<<nb2, TPB, 0, stream>>>(edges1, c_base, edges2, f_base, n, nb2);
  invsqrt_kernel<<<(n + TPB - 1) / TPB, TPB, 0, stream>>>(deg_out, inv_out, n);

  float* cat_base = out + (size_t)3 * n;
  for (int layer = 0; layer < 3; layer++) {
    const float* x; int ldx;
    if (layer == 0) { x = node_feat; ldx = 64; }
    else { x = cat_base + (size_t)(layer - 1) * 64; ldx = 192; }
    fused_layer<<<nbf, TPB, 0, stream>>>(x, ldx, edges2, f_base, inv_out,
        Ws[layer], bs[layer], cat_base + (size_t)layer * 64, out + (size_t)layer * n, n);
  }
}

// Round 3
// 560.067 us; speedup vs baseline: 3.5064x; 3.5064x over previous
//
#include <hip/hip_runtime.h>

// GCN: n=100k nodes, E=1.6M edges, D=64, 3 layers.
// Structure: degree -> scan(row_ptr) -> 2-level coalesced counting sort of edges by dst
//            -> per layer: spmm (1 wave/row, 8 edges in flight) + gemm/bias/relu/pool.
// Packing in edges1: (src<<9)|(dst&511), needs n <= 2^17 and src readable in 23 bits. OK for n=100k.

#define TPB 256
#define CAP_S2 10240   // LDS staging in scatter2; coarse bucket max ~8.5k << 10240

// ---------------- prep ----------------

__global__ void zero_int_kernel(int* __restrict__ p, int n) {
  int i = blockIdx.x * TPB + threadIdx.x;
  if (i < n) p[i] = 0;
}

__global__ __launch_bounds__(256) void degree_kernel(
    const int* __restrict__ src, const int* __restrict__ dst, int e,
    int* __restrict__ deg_out, int* __restrict__ deg_in) {
  int i4 = (blockIdx.x * TPB + threadIdx.x) * 4;
  if (i4 + 3 < e) {
    int4 s = *(const int4*)&src[i4];
    int4 d = *(const int4*)&dst[i4];
    atomicAdd(&deg_out[s.x], 1); atomicAdd(&deg_out[s.y], 1);
    atomicAdd(&deg_out[s.z], 1); atomicAdd(&deg_out[s.w], 1);
    atomicAdd(&deg_in[d.x], 1); atomicAdd(&deg_in[d.y], 1);
    atomicAdd(&deg_in[d.z], 1); atomicAdd(&deg_in[d.w], 1);
  } else {
    for (int i = i4; i < e; i++) {
      atomicAdd(&deg_out[src[i]], 1);
      atomicAdd(&deg_in[dst[i]], 1);
    }
  }
}

__global__ void invsqrt_kernel(const int* __restrict__ deg_out, const int* __restrict__ deg_in,
                               float* __restrict__ inv_out, float* __restrict__ inv_in, int n) {
  int i = blockIdx.x * TPB + threadIdx.x;
  if (i < n) {
    inv_out[i] = rsqrtf(fmaxf((float)deg_out[i], 1.0f));
    inv_in[i]  = rsqrtf(fmaxf((float)deg_in[i], 1.0f));
  }
}

// exclusive scan of deg_in -> row_ptr; 1024 elems per block
__global__ void scan_p1(const int* __restrict__ deg, int n, int* __restrict__ bsums) {
  int b = blockIdx.x, t = threadIdx.x;
  int base = b * 1024 + t * 4;
  int s = 0;
  #pragma unroll
  for (int i = 0; i < 4; i++) { int idx = base + i; if (idx < n) s += deg[idx]; }
  __shared__ int lds[TPB];
  lds[t] = s; __syncthreads();
  for (int off = TPB / 2; off > 0; off >>= 1) {
    if (t < off) lds[t] += lds[t + off];
    __syncthreads();
  }
  if (t == 0) bsums[b] = lds[0];
}

__global__ void scan_p2(int* __restrict__ bsums, int nb, int* __restrict__ row_ptr, int n) {
  if (threadIdx.x == 0 && blockIdx.x == 0) {
    int acc = 0;
    for (int i = 0; i < nb; i++) { int v = bsums[i]; bsums[i] = acc; acc += v; }
    row_ptr[n] = acc;
  }
}

__global__ void scan_p3(const int* __restrict__ deg, int n, const int* __restrict__ bsums,
                        int* __restrict__ row_ptr) {
  int b = blockIdx.x, t = threadIdx.x;
  int base = b * 1024 + t * 4;
  int v[4]; int s = 0;
  #pragma unroll
  for (int i = 0; i < 4; i++) { int idx = base + i; v[i] = (idx < n) ? deg[idx] : 0; s += v[i]; }
  __shared__ int lds[TPB];
  lds[t] = s; __syncthreads();
  for (int off = 1; off < TPB; off <<= 1) {
    int add = (t >= off) ? lds[t - off] : 0;
    __syncthreads();
    lds[t] += add;
    __syncthreads();
  }
  int run = bsums[b] + ((t == 0) ? 0 : lds[t - 1]);
  #pragma unroll
  for (int i = 0; i < 4; i++) {
    int idx = base + i;
    if (idx < n) { row_ptr[idx] = run; run += v[i]; }
  }
}

// c_cursor[b] = row_ptr[min(b*512, n)]
__global__ void init_ccursor(const int* __restrict__ row_ptr, int* __restrict__ c_cursor,
                             int nb2, int n) {
  int b = blockIdx.x * TPB + threadIdx.x;
  if (b < nb2) c_cursor[b] = row_ptr[min(b << 9, n)];
}

// bin edges into 512-row coarse buckets, LDS-batched cursors, packed (src<<9)|(dst&511)
__global__ __launch_bounds__(256) void scatter1(
    const int* __restrict__ src, const int* __restrict__ dst, int e,
    int* __restrict__ c_cursor, unsigned* __restrict__ edges1, int nb2) {
  __shared__ int hist[1024];
  int t = threadIdx.x;
  for (int i = t; i < nb2; i += TPB) hist[i] = 0;
  __syncthreads();
  int base = blockIdx.x * 4096;
  #pragma unroll
  for (int k = 0; k < 16; k++) {
    int i = base + t + k * TPB;
    if (i < e) atomicAdd(&hist[dst[i] >> 9], 1);
  }
  __syncthreads();
  for (int i = t; i < nb2; i += TPB) {
    int c = hist[i];
    hist[i] = c ? atomicAdd(&c_cursor[i], c) : 0;
  }
  __syncthreads();
  #pragma unroll
  for (int k = 0; k < 16; k++) {
    int i = base + t + k * TPB;
    if (i < e) {
      int d = dst[i];
      int pos = atomicAdd(&hist[d >> 9], 1);
      edges1[pos] = ((unsigned)src[i] << 9) | (unsigned)(d & 511);
    }
  }
}

// per coarse bucket: place each edge at row_ptr-exact position via LDS cursors,
// stage in LDS, write col (src indices) fully coalesced.
__global__ __launch_bounds__(256) void scatter2(
    const unsigned* __restrict__ edges1, const int* __restrict__ row_ptr,
    int* __restrict__ col, int n) {
  __shared__ int sOut[CAP_S2];
  __shared__ int cur[512];
  int b = blockIdx.x, t = threadIdx.x;
  int rstart = b << 9;
  int nrows = min(512, n - rstart);
  int s = row_ptr[rstart];
  int e = row_ptr[rstart + nrows];
  for (int r = t; r < nrows; r += TPB) cur[r] = row_ptr[rstart + r] - s;
  __syncthreads();
  for (int i = s + t; i < e; i += TPB) {
    unsigned v = edges1[i];
    int dl = (int)(v & 511u);
    int pos = atomicAdd(&cur[dl], 1);
    int sv = (int)(v >> 9);
    if (pos < CAP_S2) sOut[pos] = sv;
    else col[s + pos] = sv;   // statistically never; correctness fallback
  }
  __syncthreads();
  int m = min(e - s, CAP_S2);
  for (int k = t; k < m; k += TPB) col[s + k] = sOut[k];
}

// ---------------- SpMM: one wave per dst row, 16 lanes x float4, 8 edges in flight ----------------
__global__ __launch_bounds__(256) void spmm_kernel(const float* __restrict__ x, int ldx,
    const int* __restrict__ row_ptr, const int* __restrict__ col,
    const float* __restrict__ inv_out, float* __restrict__ agg, int n) {
  int wid = (blockIdx.x * TPB + threadIdx.x) >> 6;
  if (wid >= n) return;
  int lane = threadIdx.x & 63;
  int g = lane >> 4;            // edge group 0..3
  int f4 = (lane & 15) << 2;    // feature offset
  int s = row_ptr[wid], e = row_ptr[wid + 1];
  float ax = 0.f, ay = 0.f, az = 0.f, aw = 0.f;
  int i = s + g;
  for (; i + 4 < e; i += 8) {   // slots i and i+4 both valid
    int c0 = col[i], c1 = col[i + 4];
    float w0 = inv_out[c0], w1 = inv_out[c1];
    const float4 x0 = *(const float4*)&x[(size_t)c0 * ldx + f4];
    const float4 x1 = *(const float4*)&x[(size_t)c1 * ldx + f4];
    ax = fmaf(x0.x, w0, ax); ay = fmaf(x0.y, w0, ay);
    az = fmaf(x0.z, w0, az); aw = fmaf(x0.w, w0, aw);
    ax = fmaf(x1.x, w1, ax); ay = fmaf(x1.y, w1, ay);
    az = fmaf(x1.z, w1, az); aw = fmaf(x1.w, w1, aw);
  }
  if (i < e) {
    int c0 = col[i];
    float w0 = inv_out[c0];
    const float4 x0 = *(const float4*)&x[(size_t)c0 * ldx + f4];
    ax = fmaf(x0.x, w0, ax); ay = fmaf(x0.y, w0, ay);
    az = fmaf(x0.z, w0, az); aw = fmaf(x0.w, w0, aw);
  }
  ax += __shfl_xor(ax, 16); ax += __shfl_xor(ax, 32);
  ay += __shfl_xor(ay, 16); ay += __shfl_xor(ay, 32);
  az += __shfl_xor(az, 16); az += __shfl_xor(az, 32);
  aw += __shfl_xor(aw, 16); aw += __shfl_xor(aw, 32);
  if (g == 0) {
    float4 r = {ax, ay, az, aw};
    *(float4*)&agg[(size_t)wid * 64 + f4] = r;
  }
}

// ---------------- GEMM + bias + ReLU + strided store + row-sum pool ----------------
__global__ __launch_bounds__(256) void gemm_relu_pool(
    const float* __restrict__ agg, const float* __restrict__ inv_in,
    const float* __restrict__ W, const float* __restrict__ bias,
    float* __restrict__ out_cat, float* __restrict__ out_pool, int n) {
  __shared__ float sW[64 * 64];
  __shared__ float sXT[64][68];
  int t = threadIdx.x;
  int row0 = blockIdx.x * 64;
  for (int i = t; i < 4096; i += TPB) sW[i] = W[i];
  for (int i = t; i < 4096; i += TPB) {
    int r = i >> 6, f = i & 63;
    int row = row0 + r;
    sXT[f][r] = (row < n) ? agg[(size_t)row * 64 + f] * inv_in[row] : 0.f;
  }
  __syncthreads();
  int tj = t & 15, tr = t >> 4;
  int j4 = tj << 2, r4 = tr << 2;
  const float4 bv = *(const float4*)&bias[j4];
  float4 a0 = bv, a1 = bv, a2 = bv, a3 = bv;
  #pragma unroll 8
  for (int f = 0; f < 64; f++) {
    float4 w  = *(const float4*)&sW[f * 64 + j4];
    float4 xv = *(const float4*)&sXT[f][r4];
    a0.x = fmaf(xv.x, w.x, a0.x); a0.y = fmaf(xv.x, w.y, a0.y);
    a0.z = fmaf(xv.x, w.z, a0.z); a0.w = fmaf(xv.x, w.w, a0.w);
    a1.x = fmaf(xv.y, w.x, a1.x); a1.y = fmaf(xv.y, w.y, a1.y);
    a1.z = fmaf(xv.y, w.z, a1.z); a1.w = fmaf(xv.y, w.w, a1.w);
    a2.x = fmaf(xv.z, w.x, a2.x); a2.y = fmaf(xv.z, w.y, a2.y);
    a2.z = fmaf(xv.z, w.z, a2.z); a2.w = fmaf(xv.z, w.w, a2.w);
    a3.x = fmaf(xv.w, w.x, a3.x); a3.y = fmaf(xv.w, w.y, a3.y);
    a3.z = fmaf(xv.w, w.z, a3.z); a3.w = fmaf(xv.w, w.w, a3.w);
  }
  float4 accs[4] = {a0, a1, a2, a3};
  #pragma unroll
  for (int ri = 0; ri < 4; ri++) {
    int row = row0 + r4 + ri;
    if (row < n) {
      float4 h = accs[ri];
      h.x = fmaxf(h.x, 0.f); h.y = fmaxf(h.y, 0.f);
      h.z = fmaxf(h.z, 0.f); h.w = fmaxf(h.w, 0.f);
      *(float4*)&out_cat[(size_t)row * 192 + j4] = h;
      float part = h.x + h.y + h.z + h.w;
      part += __shfl_xor(part, 1);
      part += __shfl_xor(part, 2);
      part += __shfl_xor(part, 4);
      part += __shfl_xor(part, 8);
      if (tj == 0) out_pool[row] = part;
    }
  }
}

// ---------------- launch ----------------

extern "C" void kernel_launch(void* const* d_in, const int* in_sizes, int n_in,
                              void* d_out, int out_size, void* d_ws, size_t ws_size,
                              hipStream_t stream) {
  const float* node_feat = (const float*)d_in[0];
  const int* src = (const int*)d_in[1];
  const int* dst = (const int*)d_in[2];
  const float* Ws[3] = {(const float*)d_in[4], (const float*)d_in[6], (const float*)d_in[8]};
  const float* bs[3] = {(const float*)d_in[5], (const float*)d_in[7], (const float*)d_in[9]};
  float* out = (float*)d_out;
  int n = in_sizes[0] / 64;
  int e = in_sizes[1];
  int nb2 = (n + 511) / 512;

  char* p = (char*)d_ws;
  float* agg = (float*)p;     p += (size_t)n * 64 * sizeof(float);
  float* inv_out = (float*)p; p += (size_t)n * sizeof(float);
  float* inv_in = (float*)p;  p += (size_t)n * sizeof(float);
  int* deg = (int*)p;         p += (size_t)2 * n * sizeof(int);   // deg_out | deg_in
  int* row_ptr = (int*)p;     p += ((size_t)n + 4) * sizeof(int);
  int* c_cursor = (int*)p;    p += (size_t)nb2 * sizeof(int);
  int* bsums = (int*)p;       p += 512;
  unsigned* edges1 = (unsigned*)p; p += (size_t)e * sizeof(unsigned);
  int* col = (int*)p;         p += (size_t)e * sizeof(int);

  int* deg_out = deg;
  int* deg_in = deg + n;
  int nb = (n + 1023) / 1024;
  int eb = (e + 4095) / 4096;

  zero_int_kernel<<<(2 * n + TPB - 1) / TPB, TPB, 0, stream>>>(deg, 2 * n);
  degree_kernel<<<(e / 4 + TPB - 1) / TPB, TPB, 0, stream>>>(src, dst, e, deg_out, deg_in);
  invsqrt_kernel<<<(n + TPB - 1) / TPB, TPB, 0, stream>>>(deg_out, deg_in, inv_out, inv_in, n);
  scan_p1<<<nb, TPB, 0, stream>>>(deg_in, n, bsums);
  scan_p2<<<1, 64, 0, stream>>>(bsums, nb, row_ptr, n);
  scan_p3<<<nb, TPB, 0, stream>>>(deg_in, n, bsums, row_ptr);
  init_ccursor<<<(nb2 + TPB - 1) / TPB, TPB, 0, stream>>>(row_ptr, c_cursor, nb2, n);
  scatter1<<<eb, TPB, 0, stream>>>(src, dst, e, c_cursor, edges1, nb2);
  scatter2<<<nb2, TPB, 0, stream>>>(edges1, row_ptr, col, n);

  float* cat_base = out + (size_t)3 * n;
  for (int layer = 0; layer < 3; layer++) {
    const float* x; int ldx;
    if (layer == 0) { x = node_feat; ldx = 64; }
    else { x = cat_base + (size_t)(layer - 1) * 64; ldx = 192; }
    spmm_kernel<<<(n + 3) / 4, TPB, 0, stream>>>(x, ldx, row_ptr, col, inv_out, agg, n);
    gemm_relu_pool<<<(n + 63) / 64, TPB, 0, stream>>>(agg, inv_in, Ws[layer], bs[layer],
        cat_base + (size_t)layer * 64, out + (size_t)layer * n, n);
  }
}

// Round 4
// 444.245 us; speedup vs baseline: 4.4206x; 1.2607x over previous
//
#include <hip/hip_runtime.h>

// GCN: n=100k nodes, E=1.6M edges, D=64, 3 layers.
// No per-node global atomics anywhere: degrees come from two-level counting sort.
//   coarse_hist  : LDS histograms of src>>9 and dst>>9
//   scan_coarse  : exclusive scans of both coarse count arrays (1 block)
//   scatter_both : one read pass; bins src values by src>>9 -> srcbuf,
//                  and (src<<9|dst&511) by dst>>9 -> edges1 (LDS-batched cursors)
//   degout_fine  : per src-bucket LDS histogram -> inv_out
//   scatter2     : per dst-bucket: LDS hist + block scan -> row_ptr/inv_in,
//                  place edges, coalesced col write
//   per layer    : spmm (1 wave/row, 8 edges in flight) + gemm/bias/relu/pool
// Packing (src<<9)|(dst&511) needs n <= 2^17. srcbuf aliases col (sequential stream).

#define TPB 256
#define CAP_S2 10240   // LDS staging in scatter2; coarse bucket ~8.2k avg, >20 sigma margin

__global__ void zero_int_kernel(int* __restrict__ p, int n) {
  int i = blockIdx.x * TPB + threadIdx.x;
  if (i < n) p[i] = 0;
}

// ---------------- coarse histograms (LDS-aggregated) ----------------
__global__ __launch_bounds__(256) void coarse_hist(
    const int* __restrict__ src, const int* __restrict__ dst, int e,
    int* __restrict__ c_cnt_s, int* __restrict__ c_cnt_d) {
  __shared__ int hs[256], hd[256];
  int t = threadIdx.x;
  hs[t] = 0; hd[t] = 0;
  __syncthreads();
  int base = blockIdx.x * 4096;
  #pragma unroll
  for (int k = 0; k < 4; k++) {
    int i = base + 4 * t + 1024 * k;
    if (i + 3 < e) {
      int4 s4 = *(const int4*)&src[i];
      int4 d4 = *(const int4*)&dst[i];
      atomicAdd(&hs[s4.x >> 9], 1); atomicAdd(&hs[s4.y >> 9], 1);
      atomicAdd(&hs[s4.z >> 9], 1); atomicAdd(&hs[s4.w >> 9], 1);
      atomicAdd(&hd[d4.x >> 9], 1); atomicAdd(&hd[d4.y >> 9], 1);
      atomicAdd(&hd[d4.z >> 9], 1); atomicAdd(&hd[d4.w >> 9], 1);
    } else {
      for (int j = i; j < e && j < i + 4; j++) {
        atomicAdd(&hs[src[j] >> 9], 1);
        atomicAdd(&hd[dst[j] >> 9], 1);
      }
    }
  }
  __syncthreads();
  if (hs[t]) atomicAdd(&c_cnt_s[t], hs[t]);
  if (hd[t]) atomicAdd(&c_cnt_d[t], hd[t]);
}

// ---------------- coarse scans (1 block) ----------------
__global__ void scan_coarse(const int* __restrict__ c_cnt_s, const int* __restrict__ c_cnt_d,
                            int nbb, int* __restrict__ c_base_s, int* __restrict__ cur_s,
                            int* __restrict__ c_base_d, int* __restrict__ cur_d,
                            int* __restrict__ row_ptr, int n, int e) {
  __shared__ int lds[256];
  int t = threadIdx.x;
  int v = (t < nbb) ? c_cnt_s[t] : 0;
  lds[t] = v; __syncthreads();
  for (int off = 1; off < 256; off <<= 1) {
    int a = (t >= off) ? lds[t - off] : 0;
    __syncthreads(); lds[t] += a; __syncthreads();
  }
  if (t < nbb) { int ex = lds[t] - v; c_base_s[t] = ex; cur_s[t] = ex; }
  if (t == 0) c_base_s[nbb] = e;
  __syncthreads();
  int vd = (t < nbb) ? c_cnt_d[t] : 0;
  lds[t] = vd; __syncthreads();
  for (int off = 1; off < 256; off <<= 1) {
    int a = (t >= off) ? lds[t - off] : 0;
    __syncthreads(); lds[t] += a; __syncthreads();
  }
  if (t < nbb) { int ex = lds[t] - vd; c_base_d[t] = ex; cur_d[t] = ex; }
  if (t == 0) { c_base_d[nbb] = e; row_ptr[n] = e; }
}

// ---------------- one read pass, two coarse scatters ----------------
__global__ __launch_bounds__(256) void scatter_both(
    const int* __restrict__ src, const int* __restrict__ dst, int e,
    int* __restrict__ cur_s, int* __restrict__ cur_d,
    int* __restrict__ srcbuf, unsigned* __restrict__ edges1) {
  __shared__ int hs[256], hd[256];
  int t = threadIdx.x;
  hs[t] = 0; hd[t] = 0;
  __syncthreads();
  int base = blockIdx.x * 4096;
  int sv[16], dv[16];
  #pragma unroll
  for (int k = 0; k < 4; k++) {
    int i = base + 4 * t + 1024 * k;
    if (i + 3 < e) {
      int4 s4 = *(const int4*)&src[i];
      int4 d4 = *(const int4*)&dst[i];
      sv[4*k] = s4.x; sv[4*k+1] = s4.y; sv[4*k+2] = s4.z; sv[4*k+3] = s4.w;
      dv[4*k] = d4.x; dv[4*k+1] = d4.y; dv[4*k+2] = d4.z; dv[4*k+3] = d4.w;
    } else {
      #pragma unroll
      for (int j = 0; j < 4; j++) {
        int idx = i + j;
        if (idx < e) { sv[4*k+j] = src[idx]; dv[4*k+j] = dst[idx]; }
        else { sv[4*k+j] = -1; dv[4*k+j] = -1; }
      }
    }
  }
  #pragma unroll
  for (int k = 0; k < 16; k++) {
    if (dv[k] >= 0) {
      atomicAdd(&hs[sv[k] >> 9], 1);
      atomicAdd(&hd[dv[k] >> 9], 1);
    }
  }
  __syncthreads();
  int bs = hs[t], bd = hd[t];
  hs[t] = bs ? atomicAdd(&cur_s[t], bs) : 0;
  hd[t] = bd ? atomicAdd(&cur_d[t], bd) : 0;
  __syncthreads();
  #pragma unroll
  for (int k = 0; k < 16; k++) {
    if (dv[k] >= 0) {
      int ps = atomicAdd(&hs[sv[k] >> 9], 1);
      srcbuf[ps] = sv[k];
      int pd = atomicAdd(&hd[dv[k] >> 9], 1);
      edges1[pd] = ((unsigned)sv[k] << 9) | (unsigned)(dv[k] & 511);
    }
  }
}

// ---------------- out-degree from src-bucketed stream ----------------
__global__ __launch_bounds__(256) void degout_fine(
    const int* __restrict__ srcbuf, const int* __restrict__ c_base_s,
    float* __restrict__ inv_out, int n) {
  __shared__ int hist[512];
  int b = blockIdx.x, t = threadIdx.x;
  hist[t] = 0; hist[t + 256] = 0;
  __syncthreads();
  int s = c_base_s[b], e = c_base_s[b + 1];
  for (int i = s + t; i < e; i += TPB) atomicAdd(&hist[srcbuf[i] & 511], 1);
  __syncthreads();
  int rstart = b << 9;
  #pragma unroll
  for (int k = 0; k < 2; k++) {
    int r = t + k * 256;
    int node = rstart + r;
    if (node < n) inv_out[node] = rsqrtf(fmaxf((float)hist[r], 1.0f));
  }
}

// ---------------- fine sort by dst + row_ptr + inv_in ----------------
__global__ __launch_bounds__(256) void scatter2(
    const unsigned* __restrict__ edges1, const int* __restrict__ c_base_d,
    int* __restrict__ row_ptr, float* __restrict__ inv_in,
    int* __restrict__ col, int n) {
  __shared__ int sOut[CAP_S2];
  __shared__ int hist[512];
  __shared__ int cur[512];
  __shared__ int psum[256];
  int b = blockIdx.x, t = threadIdx.x;
  int s = c_base_d[b], e = c_base_d[b + 1];
  int rstart = b << 9;
  int nrows = min(512, n - rstart);
  hist[t] = 0; hist[t + 256] = 0;
  __syncthreads();
  for (int i = s + t; i < e; i += TPB) atomicAdd(&hist[edges1[i] & 511u], 1);
  __syncthreads();
  int h0 = hist[2 * t], h1 = hist[2 * t + 1];
  psum[t] = h0 + h1; __syncthreads();
  for (int off = 1; off < 256; off <<= 1) {
    int a = (t >= off) ? psum[t - off] : 0;
    __syncthreads(); psum[t] += a; __syncthreads();
  }
  int ex = psum[t] - (h0 + h1);             // exclusive prefix over row pairs
  cur[2 * t] = ex; cur[2 * t + 1] = ex + h0;
  if (2 * t < nrows) {
    row_ptr[rstart + 2 * t] = s + ex;
    inv_in[rstart + 2 * t] = rsqrtf(fmaxf((float)h0, 1.0f));
  }
  if (2 * t + 1 < nrows) {
    row_ptr[rstart + 2 * t + 1] = s + ex + h0;
    inv_in[rstart + 2 * t + 1] = rsqrtf(fmaxf((float)h1, 1.0f));
  }
  __syncthreads();
  for (int i = s + t; i < e; i += TPB) {
    unsigned v = edges1[i];
    int pos = atomicAdd(&cur[v & 511u], 1);
    int sv = (int)(v >> 9);
    if (pos < CAP_S2) sOut[pos] = sv;
    else col[s + pos] = sv;   // statistically never; correctness fallback
  }
  __syncthreads();
  int m = min(e - s, CAP_S2);
  for (int k = t; k < m; k += TPB) col[s + k] = sOut[k];
}

// ---------------- SpMM: one wave per dst row, 16 lanes x float4, 8 edges in flight ----------------
__global__ __launch_bounds__(256) void spmm_kernel(const float* __restrict__ x, int ldx,
    const int* __restrict__ row_ptr, const int* __restrict__ col,
    const float* __restrict__ inv_out, float* __restrict__ agg, int n) {
  int wid = (blockIdx.x * TPB + threadIdx.x) >> 6;
  if (wid >= n) return;
  int lane = threadIdx.x & 63;
  int g = lane >> 4;            // edge group 0..3
  int f4 = (lane & 15) << 2;    // feature offset
  int s = row_ptr[wid], e = row_ptr[wid + 1];
  float ax = 0.f, ay = 0.f, az = 0.f, aw = 0.f;
  int i = s + g;
  for (; i + 4 < e; i += 8) {
    int c0 = col[i], c1 = col[i + 4];
    float w0 = inv_out[c0], w1 = inv_out[c1];
    const float4 x0 = *(const float4*)&x[(size_t)c0 * ldx + f4];
    const float4 x1 = *(const float4*)&x[(size_t)c1 * ldx + f4];
    ax = fmaf(x0.x, w0, ax); ay = fmaf(x0.y, w0, ay);
    az = fmaf(x0.z, w0, az); aw = fmaf(x0.w, w0, aw);
    ax = fmaf(x1.x, w1, ax); ay = fmaf(x1.y, w1, ay);
    az = fmaf(x1.z, w1, az); aw = fmaf(x1.w, w1, aw);
  }
  if (i < e) {
    int c0 = col[i];
    float w0 = inv_out[c0];
    const float4 x0 = *(const float4*)&x[(size_t)c0 * ldx + f4];
    ax = fmaf(x0.x, w0, ax); ay = fmaf(x0.y, w0, ay);
    az = fmaf(x0.z, w0, az); aw = fmaf(x0.w, w0, aw);
  }
  ax += __shfl_xor(ax, 16); ax += __shfl_xor(ax, 32);
  ay += __shfl_xor(ay, 16); ay += __shfl_xor(ay, 32);
  az += __shfl_xor(az, 16); az += __shfl_xor(az, 32);
  aw += __shfl_xor(aw, 16); aw += __shfl_xor(aw, 32);
  if (g == 0) {
    float4 r = {ax, ay, az, aw};
    *(float4*)&agg[(size_t)wid * 64 + f4] = r;
  }
}

// ---------------- GEMM + bias + ReLU + strided store + row-sum pool ----------------
__global__ __launch_bounds__(256) void gemm_relu_pool(
    const float* __restrict__ agg, const float* __restrict__ inv_in,
    const float* __restrict__ W, const float* __restrict__ bias,
    float* __restrict__ out_cat, float* __restrict__ out_pool, int n) {
  __shared__ float sW[64 * 64];
  __shared__ float sXT[64][68];
  int t = threadIdx.x;
  int row0 = blockIdx.x * 64;
  for (int i = t; i < 4096; i += TPB) sW[i] = W[i];
  for (int i = t; i < 4096; i += TPB) {
    int r = i >> 6, f = i & 63;
    int row = row0 + r;
    sXT[f][r] = (row < n) ? agg[(size_t)row * 64 + f] * inv_in[row] : 0.f;
  }
  __syncthreads();
  int tj = t & 15, tr = t >> 4;
  int j4 = tj << 2, r4 = tr << 2;
  const float4 bv = *(const float4*)&bias[j4];
  float4 a0 = bv, a1 = bv, a2 = bv, a3 = bv;
  #pragma unroll 8
  for (int f = 0; f < 64; f++) {
    float4 w  = *(const float4*)&sW[f * 64 + j4];
    float4 xv = *(const float4*)&sXT[f][r4];
    a0.x = fmaf(xv.x, w.x, a0.x); a0.y = fmaf(xv.x, w.y, a0.y);
    a0.z = fmaf(xv.x, w.z, a0.z); a0.w = fmaf(xv.x, w.w, a0.w);
    a1.x = fmaf(xv.y, w.x, a1.x); a1.y = fmaf(xv.y, w.y, a1.y);
    a1.z = fmaf(xv.y, w.z, a1.z); a1.w = fmaf(xv.y, w.w, a1.w);
    a2.x = fmaf(xv.z, w.x, a2.x); a2.y = fmaf(xv.z, w.y, a2.y);
    a2.z = fmaf(xv.z, w.z, a2.z); a2.w = fmaf(xv.z, w.w, a2.w);
    a3.x = fmaf(xv.w, w.x, a3.x); a3.y = fmaf(xv.w, w.y, a3.y);
    a3.z = fmaf(xv.w, w.z, a3.z); a3.w = fmaf(xv.w, w.w, a3.w);
  }
  float4 accs[4] = {a0, a1, a2, a3};
  #pragma unroll
  for (int ri = 0; ri < 4; ri++) {
    int row = row0 + r4 + ri;
    if (row < n) {
      float4 h = accs[ri];
      h.x = fmaxf(h.x, 0.f); h.y = fmaxf(h.y, 0.f);
      h.z = fmaxf(h.z, 0.f); h.w = fmaxf(h.w, 0.f);
      *(float4*)&out_cat[(size_t)row * 192 + j4] = h;
      float part = h.x + h.y + h.z + h.w;
      part += __shfl_xor(part, 1);
      part += __shfl_xor(part, 2);
      part += __shfl_xor(part, 4);
      part += __shfl_xor(part, 8);
      if (tj == 0) out_pool[row] = part;
    }
  }
}

// ---------------- launch ----------------

extern "C" void kernel_launch(void* const* d_in, const int* in_sizes, int n_in,
                              void* d_out, int out_size, void* d_ws, size_t ws_size,
                              hipStream_t stream) {
  const float* node_feat = (const float*)d_in[0];
  const int* src = (const int*)d_in[1];
  const int* dst = (const int*)d_in[2];
  const float* Ws[3] = {(const float*)d_in[4], (const float*)d_in[6], (const float*)d_in[8]};
  const float* bs[3] = {(const float*)d_in[5], (const float*)d_in[7], (const float*)d_in[9]};
  float* out = (float*)d_out;
  int n = in_sizes[0] / 64;
  int e = in_sizes[1];
  int nbb = (n + 511) >> 9;     // coarse buckets (196 for n=100k)

  char* p = (char*)d_ws;
  float* agg = (float*)p;       p += (size_t)n * 64 * sizeof(float);
  float* inv_out = (float*)p;   p += (size_t)n * sizeof(float);
  float* inv_in = (float*)p;    p += (size_t)n * sizeof(float);
  int* row_ptr = (int*)p;       p += ((size_t)n + 4) * sizeof(int);
  int* c_cnt_s = (int*)p;       p += 256 * sizeof(int);
  int* c_cnt_d = (int*)p;       p += 256 * sizeof(int);
  int* c_base_s = (int*)p;      p += 260 * sizeof(int);
  int* cur_s = (int*)p;         p += 256 * sizeof(int);
  int* c_base_d = (int*)p;      p += 260 * sizeof(int);
  int* cur_d = (int*)p;         p += 256 * sizeof(int);
  unsigned* edges1 = (unsigned*)p; p += (size_t)e * sizeof(unsigned);
  int* col = (int*)p;           p += (size_t)e * sizeof(int);
  int* srcbuf = col;            // alias: degout_fine consumes srcbuf before scatter2 writes col

  int eb = (e + 4095) / 4096;

  zero_int_kernel<<<2, TPB, 0, stream>>>(c_cnt_s, 512);  // c_cnt_s + c_cnt_d contiguous
  coarse_hist<<<eb, TPB, 0, stream>>>(src, dst, e, c_cnt_s, c_cnt_d);
  scan_coarse<<<1, TPB, 0, stream>>>(c_cnt_s, c_cnt_d, nbb, c_base_s, cur_s,
                                     c_base_d, cur_d, row_ptr, n, e);
  scatter_both<<<eb, TPB, 0, stream>>>(src, dst, e, cur_s, cur_d, srcbuf, edges1);
  degout_fine<<<nbb, TPB, 0, stream>>>(srcbuf, c_base_s, inv_out, n);
  scatter2<<<nbb, TPB, 0, stream>>>(edges1, c_base_d, row_ptr, inv_in, col, n);

  float* cat_base = out + (size_t)3 * n;
  for (int layer = 0; layer < 3; layer++) {
    const float* x; int ldx;
    if (layer == 0) { x = node_feat; ldx = 64; }
    else { x = cat_base + (size_t)(layer - 1) * 64; ldx = 192; }
    spmm_kernel<<<(n + 3) / 4, TPB, 0, stream>>>(x, ldx, row_ptr, col, inv_out, agg, n);
    gemm_relu_pool<<<(n + 63) / 64, TPB, 0, stream>>>(agg, inv_in, Ws[layer], bs[layer],
        cat_base + (size_t)layer * 64, out + (size_t)layer * n, n);
  }
}

// Round 5
// 415.242 us; speedup vs baseline: 4.7294x; 1.0698x over previous
//
#include <hip/hip_runtime.h>

// GCN: n=100k nodes, E=1.6M edges, D=64, 3 layers.
// Round 5: (1) spmm gathers a PRE-SCALED bf16 feature copy (xb = h*inv_out), halving
// gather traffic and removing per-edge weight loads; (2) coarse histogram is computed
// once per block and stored (no global atomics), scatter reads precomputed cursors.
// Packing (src<<9)|(dst&511) needs n <= 2^17.

#define TPB 256
#define CAP_S2 10240   // LDS staging in scatter2; dst bucket ~8.2k avg, big margin

__device__ __forceinline__ unsigned short f2bf(float f) {   // RNE fp32->bf16
  unsigned u = __float_as_uint(f);
  u += 0x7fff + ((u >> 16) & 1);
  return (unsigned short)(u >> 16);
}
__device__ __forceinline__ float bflo(unsigned u) { return __uint_as_float(u << 16); }
__device__ __forceinline__ float bfhi(unsigned u) { return __uint_as_float(u & 0xffff0000u); }

// ---------------- per-block coarse histograms (no global atomics) ----------------
__global__ __launch_bounds__(256) void coarse_hist(
    const int* __restrict__ src, const int* __restrict__ dst, int e,
    int* __restrict__ bhS, int* __restrict__ bhD) {
  __shared__ int hs[256], hd[256];
  int t = threadIdx.x, b = blockIdx.x;
  hs[t] = 0; hd[t] = 0;
  __syncthreads();
  int base = b * 4096;
  #pragma unroll
  for (int k = 0; k < 4; k++) {
    int i = base + 4 * t + 1024 * k;
    if (i + 3 < e) {
      int4 s4 = *(const int4*)&src[i];
      int4 d4 = *(const int4*)&dst[i];
      atomicAdd(&hs[s4.x >> 9], 1); atomicAdd(&hs[s4.y >> 9], 1);
      atomicAdd(&hs[s4.z >> 9], 1); atomicAdd(&hs[s4.w >> 9], 1);
      atomicAdd(&hd[d4.x >> 9], 1); atomicAdd(&hd[d4.y >> 9], 1);
      atomicAdd(&hd[d4.z >> 9], 1); atomicAdd(&hd[d4.w >> 9], 1);
    } else {
      for (int j = i; j < e && j < i + 4; j++) {
        atomicAdd(&hs[src[j] >> 9], 1);
        atomicAdd(&hd[dst[j] >> 9], 1);
      }
    }
  }
  __syncthreads();
  bhS[b * 256 + t] = hs[t];
  bhD[b * 256 + t] = hd[t];
}

// ---------------- column-scan per-block hists -> per-block cursors + bucket bases ----------------
// grid=2: block 0 handles S, block 1 handles D. In-place: bh[b][t] becomes exclusive
// prefix of bucket t over blocks 0..b-1 (relative to bucket base).
__global__ __launch_bounds__(256) void scan_blocks(
    int* __restrict__ bhS, int* __restrict__ bhD, int nblk, int nbb,
    int* __restrict__ c_base_s, int* __restrict__ c_base_d,
    int* __restrict__ row_ptr, int n, int e) {
  __shared__ int lds[256];
  int t = threadIdx.x;
  int* bh = (blockIdx.x == 0) ? bhS : bhD;
  int run = 0;
  int b = 0;
  for (; b + 3 < nblk; b += 4) {
    int i0 = (b + 0) * 256 + t, i1 = (b + 1) * 256 + t;
    int i2 = (b + 2) * 256 + t, i3 = (b + 3) * 256 + t;
    int v0 = bh[i0], v1 = bh[i1], v2 = bh[i2], v3 = bh[i3];
    bh[i0] = run; run += v0;
    bh[i1] = run; run += v1;
    bh[i2] = run; run += v2;
    bh[i3] = run; run += v3;
  }
  for (; b < nblk; b++) {
    int i0 = b * 256 + t;
    int v0 = bh[i0];
    bh[i0] = run; run += v0;
  }
  lds[t] = run; __syncthreads();
  for (int off = 1; off < 256; off <<= 1) {
    int a = (t >= off) ? lds[t - off] : 0;
    __syncthreads(); lds[t] += a; __syncthreads();
  }
  int ex = lds[t] - run;                    // exclusive prefix over buckets
  int* cb = (blockIdx.x == 0) ? c_base_s : c_base_d;
  cb[t] = ex;                               // buckets >= nbb get ex == e (empty)
  if (t == 0) cb[256] = e;
  if (blockIdx.x == 1 && t == 0) row_ptr[n] = e;
}

// ---------------- one read pass, two coarse scatters (cursors precomputed) ----------------
__global__ __launch_bounds__(256) void scatter_both(
    const int* __restrict__ src, const int* __restrict__ dst, int e,
    const int* __restrict__ bhS, const int* __restrict__ bhD,
    const int* __restrict__ c_base_s, const int* __restrict__ c_base_d,
    int* __restrict__ srcbuf, unsigned* __restrict__ edges1) {
  __shared__ int hs[256], hd[256];
  int t = threadIdx.x, b = blockIdx.x;
  hs[t] = bhS[b * 256 + t] + c_base_s[t];
  hd[t] = bhD[b * 256 + t] + c_base_d[t];
  __syncthreads();
  int base = b * 4096;
  #pragma unroll
  for (int k = 0; k < 4; k++) {
    int i = base + 4 * t + 1024 * k;
    if (i + 3 < e) {
      int4 s4 = *(const int4*)&src[i];
      int4 d4 = *(const int4*)&dst[i];
      int sv[4] = {s4.x, s4.y, s4.z, s4.w};
      int dv[4] = {d4.x, d4.y, d4.z, d4.w};
      #pragma unroll
      for (int j = 0; j < 4; j++) {
        int ps = atomicAdd(&hs[sv[j] >> 9], 1);
        srcbuf[ps] = sv[j];
        int pd = atomicAdd(&hd[dv[j] >> 9], 1);
        edges1[pd] = ((unsigned)sv[j] << 9) | (unsigned)(dv[j] & 511);
      }
    } else {
      for (int j = i; j < e && j < i + 4; j++) {
        int s = src[j], d = dst[j];
        int ps = atomicAdd(&hs[s >> 9], 1);
        srcbuf[ps] = s;
        int pd = atomicAdd(&hd[d >> 9], 1);
        edges1[pd] = ((unsigned)s << 9) | (unsigned)(d & 511);
      }
    }
  }
}

// ---------------- out-degree from src-bucketed stream ----------------
__global__ __launch_bounds__(256) void degout_fine(
    const int* __restrict__ srcbuf, const int* __restrict__ c_base_s,
    float* __restrict__ inv_out, int n) {
  __shared__ int hist[512];
  int b = blockIdx.x, t = threadIdx.x;
  hist[t] = 0; hist[t + 256] = 0;
  __syncthreads();
  int s = c_base_s[b], e = c_base_s[b + 1];
  for (int i = s + t; i < e; i += TPB) atomicAdd(&hist[srcbuf[i] & 511], 1);
  __syncthreads();
  int rstart = b << 9;
  #pragma unroll
  for (int k = 0; k < 2; k++) {
    int r = t + k * 256;
    int node = rstart + r;
    if (node < n) inv_out[node] = rsqrtf(fmaxf((float)hist[r], 1.0f));
  }
}

// ---------------- layer-0 pre-scaled bf16 copy: xb[i,:] = bf16(node_feat[i,:]*inv_out[i]) ---------
__global__ __launch_bounds__(256) void cast_scale(
    const float* __restrict__ x, const float* __restrict__ inv_out,
    unsigned short* __restrict__ xb, int total) {   // total = n*64
  int i4 = (blockIdx.x * TPB + threadIdx.x) * 4;
  if (i4 >= total) return;
  float sc = inv_out[i4 >> 6];
  float4 v = *(const float4*)&x[i4];
  ushort4 o;
  o.x = f2bf(v.x * sc); o.y = f2bf(v.y * sc);
  o.z = f2bf(v.z * sc); o.w = f2bf(v.w * sc);
  *(ushort4*)&xb[i4] = o;
}

// ---------------- fine sort by dst + row_ptr + inv_in ----------------
__global__ __launch_bounds__(256) void scatter2(
    const unsigned* __restrict__ edges1, const int* __restrict__ c_base_d,
    int* __restrict__ row_ptr, float* __restrict__ inv_in,
    int* __restrict__ col, int n) {
  __shared__ int sOut[CAP_S2];
  __shared__ int hist[512];
  __shared__ int cur[512];
  __shared__ int psum[256];
  int b = blockIdx.x, t = threadIdx.x;
  int s = c_base_d[b], e = c_base_d[b + 1];
  int rstart = b << 9;
  int nrows = min(512, n - rstart);
  hist[t] = 0; hist[t + 256] = 0;
  __syncthreads();
  for (int i = s + t; i < e; i += TPB) atomicAdd(&hist[edges1[i] & 511u], 1);
  __syncthreads();
  int h0 = hist[2 * t], h1 = hist[2 * t + 1];
  psum[t] = h0 + h1; __syncthreads();
  for (int off = 1; off < 256; off <<= 1) {
    int a = (t >= off) ? psum[t - off] : 0;
    __syncthreads(); psum[t] += a; __syncthreads();
  }
  int ex = psum[t] - (h0 + h1);
  cur[2 * t] = ex; cur[2 * t + 1] = ex + h0;
  if (2 * t < nrows) {
    row_ptr[rstart + 2 * t] = s + ex;
    inv_in[rstart + 2 * t] = rsqrtf(fmaxf((float)h0, 1.0f));
  }
  if (2 * t + 1 < nrows) {
    row_ptr[rstart + 2 * t + 1] = s + ex + h0;
    inv_in[rstart + 2 * t + 1] = rsqrtf(fmaxf((float)h1, 1.0f));
  }
  __syncthreads();
  for (int i = s + t; i < e; i += TPB) {
    unsigned v = edges1[i];
    int pos = atomicAdd(&cur[v & 511u], 1);
    int sv = (int)(v >> 9);
    if (pos < CAP_S2) sOut[pos] = sv;
    else col[s + pos] = sv;   // statistically never; correctness fallback
  }
  __syncthreads();
  int m = min(e - s, CAP_S2);
  for (int k = t; k < m; k += TPB) col[s + k] = sOut[k];
}

// ---------------- SpMM over bf16 pre-scaled rows: 1 wave/row, 16 lanes x 4 feats ----------------
__global__ __launch_bounds__(256) void spmm_bf16(
    const unsigned short* __restrict__ xb,
    const int* __restrict__ row_ptr, const int* __restrict__ col,
    float* __restrict__ agg, int n) {
  int wid = (blockIdx.x * TPB + threadIdx.x) >> 6;
  if (wid >= n) return;
  int lane = threadIdx.x & 63;
  int g = lane >> 4;            // edge group 0..3
  int f4 = (lane & 15) << 2;    // feature offset (4 features = 8 bytes)
  int s = row_ptr[wid], e = row_ptr[wid + 1];
  float ax = 0.f, ay = 0.f, az = 0.f, aw = 0.f;
  int i = s + g;
  for (; i + 4 < e; i += 8) {   // 2 gathers in flight per lane
    int c0 = col[i], c1 = col[i + 4];
    uint2 r0 = *(const uint2*)&xb[(size_t)c0 * 64 + f4];
    uint2 r1 = *(const uint2*)&xb[(size_t)c1 * 64 + f4];
    ax += bflo(r0.x); ay += bfhi(r0.x); az += bflo(r0.y); aw += bfhi(r0.y);
    ax += bflo(r1.x); ay += bfhi(r1.x); az += bflo(r1.y); aw += bfhi(r1.y);
  }
  if (i < e) {
    int c0 = col[i];
    uint2 r0 = *(const uint2*)&xb[(size_t)c0 * 64 + f4];
    ax += bflo(r0.x); ay += bfhi(r0.x); az += bflo(r0.y); aw += bfhi(r0.y);
  }
  ax += __shfl_xor(ax, 16); ax += __shfl_xor(ax, 32);
  ay += __shfl_xor(ay, 16); ay += __shfl_xor(ay, 32);
  az += __shfl_xor(az, 16); az += __shfl_xor(az, 32);
  aw += __shfl_xor(aw, 16); aw += __shfl_xor(aw, 32);
  if (g == 0) {
    float4 r = {ax, ay, az, aw};
    *(float4*)&agg[(size_t)wid * 64 + f4] = r;
  }
}

// ---------------- GEMM + bias + ReLU + pool + (optional) next-layer bf16 copy ----------------
__global__ __launch_bounds__(256) void gemm_relu_pool(
    const float* __restrict__ agg, const float* __restrict__ inv_in,
    const float* __restrict__ inv_out,
    const float* __restrict__ W, const float* __restrict__ bias,
    float* __restrict__ out_cat, float* __restrict__ out_pool,
    unsigned short* __restrict__ xb_next, int n) {
  __shared__ float sW[64 * 64];
  __shared__ float sXT[64][68];
  int t = threadIdx.x;
  int row0 = blockIdx.x * 64;
  for (int i = t; i < 4096; i += TPB) sW[i] = W[i];
  for (int i = t; i < 4096; i += TPB) {
    int r = i >> 6, f = i & 63;
    int row = row0 + r;
    sXT[f][r] = (row < n) ? agg[(size_t)row * 64 + f] * inv_in[row] : 0.f;
  }
  __syncthreads();
  int tj = t & 15, tr = t >> 4;
  int j4 = tj << 2, r4 = tr << 2;
  const float4 bv = *(const float4*)&bias[j4];
  float4 a0 = bv, a1 = bv, a2 = bv, a3 = bv;
  #pragma unroll 8
  for (int f = 0; f < 64; f++) {
    float4 w  = *(const float4*)&sW[f * 64 + j4];
    float4 xv = *(const float4*)&sXT[f][r4];
    a0.x = fmaf(xv.x, w.x, a0.x); a0.y = fmaf(xv.x, w.y, a0.y);
    a0.z = fmaf(xv.x, w.z, a0.z); a0.w = fmaf(xv.x, w.w, a0.w);
    a1.x = fmaf(xv.y, w.x, a1.x); a1.y = fmaf(xv.y, w.y, a1.y);
    a1.z = fmaf(xv.y, w.z, a1.z); a1.w = fmaf(xv.y, w.w, a1.w);
    a2.x = fmaf(xv.z, w.x, a2.x); a2.y = fmaf(xv.z, w.y, a2.y);
    a2.z = fmaf(xv.z, w.z, a2.z); a2.w = fmaf(xv.z, w.w, a2.w);
    a3.x = fmaf(xv.w, w.x, a3.x); a3.y = fmaf(xv.w, w.y, a3.y);
    a3.z = fmaf(xv.w, w.z, a3.z); a3.w = fmaf(xv.w, w.w, a3.w);
  }
  float4 accs[4] = {a0, a1, a2, a3};
  #pragma unroll
  for (int ri = 0; ri < 4; ri++) {
    int row = row0 + r4 + ri;
    if (row < n) {
      float4 h = accs[ri];
      h.x = fmaxf(h.x, 0.f); h.y = fmaxf(h.y, 0.f);
      h.z = fmaxf(h.z, 0.f); h.w = fmaxf(h.w, 0.f);
      *(float4*)&out_cat[(size_t)row * 192 + j4] = h;
      if (xb_next) {
        float sc = inv_out[row];
        ushort4 o;
        o.x = f2bf(h.x * sc); o.y = f2bf(h.y * sc);
        o.z = f2bf(h.z * sc); o.w = f2bf(h.w * sc);
        *(ushort4*)&xb_next[(size_t)row * 64 + j4] = o;
      }
      float part = h.x + h.y + h.z + h.w;
      part += __shfl_xor(part, 1);
      part += __shfl_xor(part, 2);
      part += __shfl_xor(part, 4);
      part += __shfl_xor(part, 8);
      if (tj == 0) out_pool[row] = part;
    }
  }
}

// ---------------- launch ----------------

extern "C" void kernel_launch(void* const* d_in, const int* in_sizes, int n_in,
                              void* d_out, int out_size, void* d_ws, size_t ws_size,
                              hipStream_t stream) {
  const float* node_feat = (const float*)d_in[0];
  const int* src = (const int*)d_in[1];
  const int* dst = (const int*)d_in[2];
  const float* Ws[3] = {(const float*)d_in[4], (const float*)d_in[6], (const float*)d_in[8]};
  const float* bs[3] = {(const float*)d_in[5], (const float*)d_in[7], (const float*)d_in[9]};
  float* out = (float*)d_out;
  int n = in_sizes[0] / 64;
  int e = in_sizes[1];
  int nbb = (n + 511) >> 9;         // coarse buckets (196 for n=100k)
  int nblk = (e + 4095) / 4096;     // edge blocks (391)

  char* p = (char*)d_ws;
  float* agg = (float*)p;       p += (size_t)n * 64 * sizeof(float);
  unsigned short* xb = (unsigned short*)p; p += (size_t)n * 64 * sizeof(unsigned short);
  float* inv_out = (float*)p;   p += (size_t)n * sizeof(float);
  float* inv_in = (float*)p;    p += (size_t)n * sizeof(float);
  int* row_ptr = (int*)p;       p += ((size_t)n + 4) * sizeof(int);
  int* c_base_s = (int*)p;      p += 260 * sizeof(int);
  int* c_base_d = (int*)p;      p += 260 * sizeof(int);
  int* bhS = (int*)p;           p += (size_t)nblk * 256 * sizeof(int);
  int* bhD = (int*)p;           p += (size_t)nblk * 256 * sizeof(int);
  unsigned* edges1 = (unsigned*)p; p += (size_t)e * sizeof(unsigned);
  int* col = (int*)p;           p += (size_t)e * sizeof(int);
  int* srcbuf = col;            // alias: degout_fine consumes srcbuf before scatter2 writes col

  coarse_hist<<<nblk, TPB, 0, stream>>>(src, dst, e, bhS, bhD);
  scan_blocks<<<2, TPB, 0, stream>>>(bhS, bhD, nblk, nbb, c_base_s, c_base_d, row_ptr, n, e);
  scatter_both<<<nblk, TPB, 0, stream>>>(src, dst, e, bhS, bhD, c_base_s, c_base_d,
                                         srcbuf, edges1);
  degout_fine<<<nbb, TPB, 0, stream>>>(srcbuf, c_base_s, inv_out, n);
  cast_scale<<<(n * 64 / 4 + TPB - 1) / TPB, TPB, 0, stream>>>(node_feat, inv_out, xb, n * 64);
  scatter2<<<nbb, TPB, 0, stream>>>(edges1, c_base_d, row_ptr, inv_in, col, n);

  float* cat_base = out + (size_t)3 * n;
  for (int layer = 0; layer < 3; layer++) {
    spmm_bf16<<<(n + 3) / 4, TPB, 0, stream>>>(xb, row_ptr, col, agg, n);
    gemm_relu_pool<<<(n + 63) / 64, TPB, 0, stream>>>(agg, inv_in, inv_out, Ws[layer], bs[layer],
        cat_base + (size_t)layer * 64, out + (size_t)layer * n,
        (layer < 2) ? xb : (unsigned short*)nullptr, n);
  }
}

// Round 6
// 399.309 us; speedup vs baseline: 4.9181x; 1.0399x over previous
//
#include <hip/hip_runtime.h>

// GCN: n=100k nodes, E=1.6M edges, D=64, 3 layers.
// Round 6: spmm = 8 lanes/row x uint4 x 8 edge groups, 16 gathers in flight/wave;
// degout+cast fused (block owns its 512-node range); gemm sW load vectorized.
// Packing (src<<9)|(dst&511) needs n <= 2^17.

#define TPB 256
#define CAP_S2 10240   // LDS staging in scatter2; dst bucket ~8.2k avg, big margin

__device__ __forceinline__ unsigned short f2bf(float f) {   // RNE fp32->bf16
  unsigned u = __float_as_uint(f);
  u += 0x7fff + ((u >> 16) & 1);
  return (unsigned short)(u >> 16);
}
__device__ __forceinline__ float bflo(unsigned u) { return __uint_as_float(u << 16); }
__device__ __forceinline__ float bfhi(unsigned u) { return __uint_as_float(u & 0xffff0000u); }

// ---------------- per-block coarse histograms (no global atomics) ----------------
__global__ __launch_bounds__(256) void coarse_hist(
    const int* __restrict__ src, const int* __restrict__ dst, int e,
    int* __restrict__ bhS, int* __restrict__ bhD) {
  __shared__ int hs[256], hd[256];
  int t = threadIdx.x, b = blockIdx.x;
  hs[t] = 0; hd[t] = 0;
  __syncthreads();
  int base = b * 4096;
  #pragma unroll
  for (int k = 0; k < 4; k++) {
    int i = base + 4 * t + 1024 * k;
    if (i + 3 < e) {
      int4 s4 = *(const int4*)&src[i];
      int4 d4 = *(const int4*)&dst[i];
      atomicAdd(&hs[s4.x >> 9], 1); atomicAdd(&hs[s4.y >> 9], 1);
      atomicAdd(&hs[s4.z >> 9], 1); atomicAdd(&hs[s4.w >> 9], 1);
      atomicAdd(&hd[d4.x >> 9], 1); atomicAdd(&hd[d4.y >> 9], 1);
      atomicAdd(&hd[d4.z >> 9], 1); atomicAdd(&hd[d4.w >> 9], 1);
    } else {
      for (int j = i; j < e && j < i + 4; j++) {
        atomicAdd(&hs[src[j] >> 9], 1);
        atomicAdd(&hd[dst[j] >> 9], 1);
      }
    }
  }
  __syncthreads();
  bhS[b * 256 + t] = hs[t];
  bhD[b * 256 + t] = hd[t];
}

// ---------------- column-scan per-block hists -> per-block cursors + bucket bases ----------------
__global__ __launch_bounds__(256) void scan_blocks(
    int* __restrict__ bhS, int* __restrict__ bhD, int nblk, int nbb,
    int* __restrict__ c_base_s, int* __restrict__ c_base_d,
    int* __restrict__ row_ptr, int n, int e) {
  __shared__ int lds[256];
  int t = threadIdx.x;
  int* bh = (blockIdx.x == 0) ? bhS : bhD;
  int run = 0;
  int b = 0;
  for (; b + 3 < nblk; b += 4) {
    int i0 = (b + 0) * 256 + t, i1 = (b + 1) * 256 + t;
    int i2 = (b + 2) * 256 + t, i3 = (b + 3) * 256 + t;
    int v0 = bh[i0], v1 = bh[i1], v2 = bh[i2], v3 = bh[i3];
    bh[i0] = run; run += v0;
    bh[i1] = run; run += v1;
    bh[i2] = run; run += v2;
    bh[i3] = run; run += v3;
  }
  for (; b < nblk; b++) {
    int i0 = b * 256 + t;
    int v0 = bh[i0];
    bh[i0] = run; run += v0;
  }
  lds[t] = run; __syncthreads();
  for (int off = 1; off < 256; off <<= 1) {
    int a = (t >= off) ? lds[t - off] : 0;
    __syncthreads(); lds[t] += a; __syncthreads();
  }
  int ex = lds[t] - run;                    // exclusive prefix over buckets
  int* cb = (blockIdx.x == 0) ? c_base_s : c_base_d;
  cb[t] = ex;
  if (t == 0) cb[256] = e;
  if (blockIdx.x == 1 && t == 0) row_ptr[n] = e;
}

// ---------------- one read pass, two coarse scatters (cursors precomputed) ----------------
__global__ __launch_bounds__(256) void scatter_both(
    const int* __restrict__ src, const int* __restrict__ dst, int e,
    const int* __restrict__ bhS, const int* __restrict__ bhD,
    const int* __restrict__ c_base_s, const int* __restrict__ c_base_d,
    int* __restrict__ srcbuf, unsigned* __restrict__ edges1) {
  __shared__ int hs[256], hd[256];
  int t = threadIdx.x, b = blockIdx.x;
  hs[t] = bhS[b * 256 + t] + c_base_s[t];
  hd[t] = bhD[b * 256 + t] + c_base_d[t];
  __syncthreads();
  int base = b * 4096;
  #pragma unroll
  for (int k = 0; k < 4; k++) {
    int i = base + 4 * t + 1024 * k;
    if (i + 3 < e) {
      int4 s4 = *(const int4*)&src[i];
      int4 d4 = *(const int4*)&dst[i];
      int sv[4] = {s4.x, s4.y, s4.z, s4.w};
      int dv[4] = {d4.x, d4.y, d4.z, d4.w};
      #pragma unroll
      for (int j = 0; j < 4; j++) {
        int ps = atomicAdd(&hs[sv[j] >> 9], 1);
        srcbuf[ps] = sv[j];
        int pd = atomicAdd(&hd[dv[j] >> 9], 1);
        edges1[pd] = ((unsigned)sv[j] << 9) | (unsigned)(dv[j] & 511);
      }
    } else {
      for (int j = i; j < e && j < i + 4; j++) {
        int s = src[j], d = dst[j];
        int ps = atomicAdd(&hs[s >> 9], 1);
        srcbuf[ps] = s;
        int pd = atomicAdd(&hd[d >> 9], 1);
        edges1[pd] = ((unsigned)s << 9) | (unsigned)(d & 511);
      }
    }
  }
}

// ---------------- out-degree + pre-scaled bf16 cast (block owns nodes [b*512, b*512+512)) -------
__global__ __launch_bounds__(256) void degout_cast(
    const int* __restrict__ srcbuf, const int* __restrict__ c_base_s,
    const float* __restrict__ node_feat, float* __restrict__ inv_out,
    unsigned short* __restrict__ xb, int n) {
  __shared__ int hist[512];
  __shared__ float sInv[512];
  int b = blockIdx.x, t = threadIdx.x;
  hist[t] = 0; hist[t + 256] = 0;
  __syncthreads();
  int s = c_base_s[b], e = c_base_s[b + 1];
  for (int i = s + t; i < e; i += TPB) atomicAdd(&hist[srcbuf[i] & 511], 1);
  __syncthreads();
  int rstart = b << 9;
  int nrows = min(512, n - rstart);
  #pragma unroll
  for (int k = 0; k < 2; k++) {
    int r = t + k * 256;
    if (r < nrows) {
      float iv = rsqrtf(fmaxf((float)hist[r], 1.0f));
      sInv[r] = iv;
      inv_out[rstart + r] = iv;
    }
  }
  __syncthreads();
  int total4 = nrows * 16;                  // 64 feats = 16 float4 per row
  const float* xbase = node_feat + (size_t)rstart * 64;
  unsigned short* obase = xb + (size_t)rstart * 64;
  for (int u = t; u < total4; u += TPB) {
    int r = u >> 4;
    float sc = sInv[r];
    float4 v = *(const float4*)&xbase[(size_t)u * 4];
    ushort4 o;
    o.x = f2bf(v.x * sc); o.y = f2bf(v.y * sc);
    o.z = f2bf(v.z * sc); o.w = f2bf(v.w * sc);
    *(ushort4*)&obase[(size_t)u * 4] = o;
  }
}

// ---------------- fine sort by dst + row_ptr + inv_in ----------------
__global__ __launch_bounds__(256) void scatter2(
    const unsigned* __restrict__ edges1, const int* __restrict__ c_base_d,
    int* __restrict__ row_ptr, float* __restrict__ inv_in,
    int* __restrict__ col, int n) {
  __shared__ int sOut[CAP_S2];
  __shared__ int hist[512];
  __shared__ int cur[512];
  __shared__ int psum[256];
  int b = blockIdx.x, t = threadIdx.x;
  int s = c_base_d[b], e = c_base_d[b + 1];
  int rstart = b << 9;
  int nrows = min(512, n - rstart);
  hist[t] = 0; hist[t + 256] = 0;
  __syncthreads();
  for (int i = s + t; i < e; i += TPB) atomicAdd(&hist[edges1[i] & 511u], 1);
  __syncthreads();
  int h0 = hist[2 * t], h1 = hist[2 * t + 1];
  psum[t] = h0 + h1; __syncthreads();
  for (int off = 1; off < 256; off <<= 1) {
    int a = (t >= off) ? psum[t - off] : 0;
    __syncthreads(); psum[t] += a; __syncthreads();
  }
  int ex = psum[t] - (h0 + h1);
  cur[2 * t] = ex; cur[2 * t + 1] = ex + h0;
  if (2 * t < nrows) {
    row_ptr[rstart + 2 * t] = s + ex;
    inv_in[rstart + 2 * t] = rsqrtf(fmaxf((float)h0, 1.0f));
  }
  if (2 * t + 1 < nrows) {
    row_ptr[rstart + 2 * t + 1] = s + ex + h0;
    inv_in[rstart + 2 * t + 1] = rsqrtf(fmaxf((float)h1, 1.0f));
  }
  __syncthreads();
  for (int i = s + t; i < e; i += TPB) {
    unsigned v = edges1[i];
    int pos = atomicAdd(&cur[v & 511u], 1);
    int sv = (int)(v >> 9);
    if (pos < CAP_S2) sOut[pos] = sv;
    else col[s + pos] = sv;   // statistically never; correctness fallback
  }
  __syncthreads();
  int m = min(e - s, CAP_S2);
  for (int k = t; k < m; k += TPB) col[s + k] = sOut[k];
}

// ---------------- SpMM: 1 wave/row, 8 lanes x uint4, 8 edge groups, 16 gathers in flight --------
__global__ __launch_bounds__(256) void spmm_bf16(
    const unsigned short* __restrict__ xb,
    const int* __restrict__ row_ptr, const int* __restrict__ col,
    float* __restrict__ agg, int n) {
  int wid = (blockIdx.x * TPB + threadIdx.x) >> 6;
  if (wid >= n) return;
  int lane = threadIdx.x & 63;
  int g = lane >> 3;            // edge group 0..7
  int l8 = (lane & 7) << 3;     // feature offset (8 feats = 16 B)
  int s = row_ptr[wid], e = row_ptr[wid + 1];
  float a0 = 0, a1 = 0, a2 = 0, a3 = 0, a4 = 0, a5 = 0, a6 = 0, a7 = 0;
  int i = s + g;
  for (; i + 8 < e; i += 16) {   // 16 edges in flight per wave (2 uint4 loads/lane)
    int c0 = col[i], c1 = col[i + 8];
    uint4 r0 = *(const uint4*)&xb[(size_t)c0 * 64 + l8];
    uint4 r1 = *(const uint4*)&xb[(size_t)c1 * 64 + l8];
    a0 += bflo(r0.x); a1 += bfhi(r0.x); a2 += bflo(r0.y); a3 += bfhi(r0.y);
    a4 += bflo(r0.z); a5 += bfhi(r0.z); a6 += bflo(r0.w); a7 += bfhi(r0.w);
    a0 += bflo(r1.x); a1 += bfhi(r1.x); a2 += bflo(r1.y); a3 += bfhi(r1.y);
    a4 += bflo(r1.z); a5 += bfhi(r1.z); a6 += bflo(r1.w); a7 += bfhi(r1.w);
  }
  if (i < e) {
    int c0 = col[i];
    uint4 r0 = *(const uint4*)&xb[(size_t)c0 * 64 + l8];
    a0 += bflo(r0.x); a1 += bfhi(r0.x); a2 += bflo(r0.y); a3 += bfhi(r0.y);
    a4 += bflo(r0.z); a5 += bfhi(r0.z); a6 += bflo(r0.w); a7 += bfhi(r0.w);
  }
  a0 += __shfl_xor(a0, 8); a0 += __shfl_xor(a0, 16); a0 += __shfl_xor(a0, 32);
  a1 += __shfl_xor(a1, 8); a1 += __shfl_xor(a1, 16); a1 += __shfl_xor(a1, 32);
  a2 += __shfl_xor(a2, 8); a2 += __shfl_xor(a2, 16); a2 += __shfl_xor(a2, 32);
  a3 += __shfl_xor(a3, 8); a3 += __shfl_xor(a3, 16); a3 += __shfl_xor(a3, 32);
  a4 += __shfl_xor(a4, 8); a4 += __shfl_xor(a4, 16); a4 += __shfl_xor(a4, 32);
  a5 += __shfl_xor(a5, 8); a5 += __shfl_xor(a5, 16); a5 += __shfl_xor(a5, 32);
  a6 += __shfl_xor(a6, 8); a6 += __shfl_xor(a6, 16); a6 += __shfl_xor(a6, 32);
  a7 += __shfl_xor(a7, 8); a7 += __shfl_xor(a7, 16); a7 += __shfl_xor(a7, 32);
  if (g == 0) {
    float4 lo = {a0, a1, a2, a3};
    float4 hi = {a4, a5, a6, a7};
    *(float4*)&agg[(size_t)wid * 64 + l8] = lo;
    *(float4*)&agg[(size_t)wid * 64 + l8 + 4] = hi;
  }
}

// ---------------- GEMM + bias + ReLU + pool + (optional) next-layer bf16 copy ----------------
__global__ __launch_bounds__(256) void gemm_relu_pool(
    const float* __restrict__ agg, const float* __restrict__ inv_in,
    const float* __restrict__ inv_out,
    const float* __restrict__ W, const float* __restrict__ bias,
    float* __restrict__ out_cat, float* __restrict__ out_pool,
    unsigned short* __restrict__ xb_next, int n) {
  __shared__ float sW[64 * 64];
  __shared__ float sXT[64][68];
  int t = threadIdx.x;
  int row0 = blockIdx.x * 64;
  for (int i4 = t * 4; i4 < 4096; i4 += 1024)
    *(float4*)&sW[i4] = *(const float4*)&W[i4];
  for (int i = t; i < 4096; i += TPB) {
    int r = i >> 6, f = i & 63;
    int row = row0 + r;
    sXT[f][r] = (row < n) ? agg[(size_t)row * 64 + f] * inv_in[row] : 0.f;
  }
  __syncthreads();
  int tj = t & 15, tr = t >> 4;
  int j4 = tj << 2, r4 = tr << 2;
  const float4 bv = *(const float4*)&bias[j4];
  float4 a0 = bv, a1 = bv, a2 = bv, a3 = bv;
  #pragma unroll 8
  for (int f = 0; f < 64; f++) {
    float4 w  = *(const float4*)&sW[f * 64 + j4];
    float4 xv = *(const float4*)&sXT[f][r4];
    a0.x = fmaf(xv.x, w.x, a0.x); a0.y = fmaf(xv.x, w.y, a0.y);
    a0.z = fmaf(xv.x, w.z, a0.z); a0.w = fmaf(xv.x, w.w, a0.w);
    a1.x = fmaf(xv.y, w.x, a1.x); a1.y = fmaf(xv.y, w.y, a1.y);
    a1.z = fmaf(xv.y, w.z, a1.z); a1.w = fmaf(xv.y, w.w, a1.w);
    a2.x = fmaf(xv.z, w.x, a2.x); a2.y = fmaf(xv.z, w.y, a2.y);
    a2.z = fmaf(xv.z, w.z, a2.z); a2.w = fmaf(xv.z, w.w, a2.w);
    a3.x = fmaf(xv.w, w.x, a3.x); a3.y = fmaf(xv.w, w.y, a3.y);
    a3.z = fmaf(xv.w, w.z, a3.z); a3.w = fmaf(xv.w, w.w, a3.w);
  }
  float4 accs[4] = {a0, a1, a2, a3};
  #pragma unroll
  for (int ri = 0; ri < 4; ri++) {
    int row = row0 + r4 + ri;
    if (row < n) {
      float4 h = accs[ri];
      h.x = fmaxf(h.x, 0.f); h.y = fmaxf(h.y, 0.f);
      h.z = fmaxf(h.z, 0.f); h.w = fmaxf(h.w, 0.f);
      *(float4*)&out_cat[(size_t)row * 192 + j4] = h;
      if (xb_next) {
        float sc = inv_out[row];
        ushort4 o;
        o.x = f2bf(h.x * sc); o.y = f2bf(h.y * sc);
        o.z = f2bf(h.z * sc); o.w = f2bf(h.w * sc);
        *(ushort4*)&xb_next[(size_t)row * 64 + j4] = o;
      }
      float part = h.x + h.y + h.z + h.w;
      part += __shfl_xor(part, 1);
      part += __shfl_xor(part, 2);
      part += __shfl_xor(part, 4);
      part += __shfl_xor(part, 8);
      if (tj == 0) out_pool[row] = part;
    }
  }
}

// ---------------- launch ----------------

extern "C" void kernel_launch(void* const* d_in, const int* in_sizes, int n_in,
                              void* d_out, int out_size, void* d_ws, size_t ws_size,
                              hipStream_t stream) {
  const float* node_feat = (const float*)d_in[0];
  const int* src = (const int*)d_in[1];
  const int* dst = (const int*)d_in[2];
  const float* Ws[3] = {(const float*)d_in[4], (const float*)d_in[6], (const float*)d_in[8]};
  const float* bs[3] = {(const float*)d_in[5], (const float*)d_in[7], (const float*)d_in[9]};
  float* out = (float*)d_out;
  int n = in_sizes[0] / 64;
  int e = in_sizes[1];
  int nbb = (n + 511) >> 9;         // coarse buckets (196 for n=100k)
  int nblk = (e + 4095) / 4096;     // edge blocks (391)

  char* p = (char*)d_ws;
  float* agg = (float*)p;       p += (size_t)n * 64 * sizeof(float);
  unsigned short* xb = (unsigned short*)p; p += (size_t)n * 64 * sizeof(unsigned short);
  float* inv_out = (float*)p;   p += (size_t)n * sizeof(float);
  float* inv_in = (float*)p;    p += (size_t)n * sizeof(float);
  int* row_ptr = (int*)p;       p += ((size_t)n + 4) * sizeof(int);
  int* c_base_s = (int*)p;      p += 260 * sizeof(int);
  int* c_base_d = (int*)p;      p += 260 * sizeof(int);
  int* bhS = (int*)p;           p += (size_t)nblk * 256 * sizeof(int);
  int* bhD = (int*)p;           p += (size_t)nblk * 256 * sizeof(int);
  unsigned* edges1 = (unsigned*)p; p += (size_t)e * sizeof(unsigned);
  int* col = (int*)p;           p += (size_t)e * sizeof(int);
  int* srcbuf = col;            // alias: degout_cast consumes srcbuf before scatter2 writes col

  coarse_hist<<<nblk, TPB, 0, stream>>>(src, dst, e, bhS, bhD);
  scan_blocks<<<2, TPB, 0, stream>>>(bhS, bhD, nblk, nbb, c_base_s, c_base_d, row_ptr, n, e);
  scatter_both<<<nblk, TPB, 0, stream>>>(src, dst, e, bhS, bhD, c_base_s, c_base_d,
                                         srcbuf, edges1);
  degout_cast<<<nbb, TPB, 0, stream>>>(srcbuf, c_base_s, node_feat, inv_out, xb, n);
  scatter2<<<nbb, TPB, 0, stream>>>(edges1, c_base_d, row_ptr, inv_in, col, n);

  float* cat_base = out + (size_t)3 * n;
  for (int layer = 0; layer < 3; layer++) {
    spmm_bf16<<<(n + 3) / 4, TPB, 0, stream>>>(xb, row_ptr, col, agg, n);
    gemm_relu_pool<<<(n + 63) / 64, TPB, 0, stream>>>(agg, inv_in, inv_out, Ws[layer], bs[layer],
        cat_base + (size_t)layer * 64, out + (size_t)layer * n,
        (layer < 2) ? xb : (unsigned short*)nullptr, n);
  }
}

// Round 7
// 361.636 us; speedup vs baseline: 5.4304x; 1.1042x over previous
//
#include <hip/hip_runtime.h>

// GCN: n=100k nodes, E=1.6M edges, D=64, 3 layers.
// Round 7: spmm does 32 edges in flight per row (clamped loads + fmaf-masking) so
// 98% of rows finish in ONE latency round; histogram scan parallelized over 512 blocks.
// Packing (src<<9)|(dst&511) needs n <= 2^17.

#define TPB 256
#define CAP_S2 10240   // LDS staging in scatter2; dst bucket ~8.2k avg, big margin

__device__ __forceinline__ unsigned short f2bf(float f) {   // RNE fp32->bf16
  unsigned u = __float_as_uint(f);
  u += 0x7fff + ((u >> 16) & 1);
  return (unsigned short)(u >> 16);
}
__device__ __forceinline__ float bflo(unsigned u) { return __uint_as_float(u << 16); }
__device__ __forceinline__ float bfhi(unsigned u) { return __uint_as_float(u & 0xffff0000u); }

// ---------------- per-block coarse histograms (no global atomics) ----------------
__global__ __launch_bounds__(256) void coarse_hist(
    const int* __restrict__ src, const int* __restrict__ dst, int e,
    int* __restrict__ bhS, int* __restrict__ bhD) {
  __shared__ int hs[256], hd[256];
  int t = threadIdx.x, b = blockIdx.x;
  hs[t] = 0; hd[t] = 0;
  __syncthreads();
  int base = b * 4096;
  #pragma unroll
  for (int k = 0; k < 4; k++) {
    int i = base + 4 * t + 1024 * k;
    if (i + 3 < e) {
      int4 s4 = *(const int4*)&src[i];
      int4 d4 = *(const int4*)&dst[i];
      atomicAdd(&hs[s4.x >> 9], 1); atomicAdd(&hs[s4.y >> 9], 1);
      atomicAdd(&hs[s4.z >> 9], 1); atomicAdd(&hs[s4.w >> 9], 1);
      atomicAdd(&hd[d4.x >> 9], 1); atomicAdd(&hd[d4.y >> 9], 1);
      atomicAdd(&hd[d4.z >> 9], 1); atomicAdd(&hd[d4.w >> 9], 1);
    } else {
      for (int j = i; j < e && j < i + 4; j++) {
        atomicAdd(&hs[src[j] >> 9], 1);
        atomicAdd(&hd[dst[j] >> 9], 1);
      }
    }
  }
  __syncthreads();
  bhS[b * 256 + t] = hs[t];
  bhD[b * 256 + t] = hd[t];
}

// ---------------- per-bucket column scan of block hists (512 blocks) ----------------
// bh[b][bucket] <- exclusive prefix over b (relative to bucket start); csum[arr*256+bucket] = total
__global__ __launch_bounds__(256) void scan_buckets(
    int* __restrict__ bhS, int* __restrict__ bhD, int nblk, int* __restrict__ csum) {
  __shared__ int lds[256];
  int t = threadIdx.x;
  int bucket = blockIdx.x & 255;
  int* bh = (blockIdx.x >> 8) ? bhD : bhS;
  int carry = 0;
  for (int c0 = 0; c0 < nblk; c0 += 256) {
    int b = c0 + t;
    int v = (b < nblk) ? bh[b * 256 + bucket] : 0;
    lds[t] = v; __syncthreads();
    for (int off = 1; off < 256; off <<= 1) {
      int a = (t >= off) ? lds[t - off] : 0;
      __syncthreads(); lds[t] += a; __syncthreads();
    }
    if (b < nblk) bh[b * 256 + bucket] = carry + lds[t] - v;
    carry += lds[255];
    __syncthreads();
  }
  if (t == 0) csum[blockIdx.x] = carry;
}

// ---------------- bucket bases from csum (1 block) ----------------
__global__ void scan_bases(const int* __restrict__ csum,
                           int* __restrict__ c_base_s, int* __restrict__ c_base_d,
                           int* __restrict__ row_ptr, int n, int e) {
  __shared__ int lds[256];
  int t = threadIdx.x;
  int v = csum[t];
  lds[t] = v; __syncthreads();
  for (int off = 1; off < 256; off <<= 1) {
    int a = (t >= off) ? lds[t - off] : 0;
    __syncthreads(); lds[t] += a; __syncthreads();
  }
  c_base_s[t] = lds[t] - v;
  if (t == 0) c_base_s[256] = e;
  __syncthreads();
  int vd = csum[256 + t];
  lds[t] = vd; __syncthreads();
  for (int off = 1; off < 256; off <<= 1) {
    int a = (t >= off) ? lds[t - off] : 0;
    __syncthreads(); lds[t] += a; __syncthreads();
  }
  c_base_d[t] = lds[t] - vd;
  if (t == 0) { c_base_d[256] = e; row_ptr[n] = e; }
}

// ---------------- one read pass, two coarse scatters (cursors precomputed) ----------------
__global__ __launch_bounds__(256) void scatter_both(
    const int* __restrict__ src, const int* __restrict__ dst, int e,
    const int* __restrict__ bhS, const int* __restrict__ bhD,
    const int* __restrict__ c_base_s, const int* __restrict__ c_base_d,
    int* __restrict__ srcbuf, unsigned* __restrict__ edges1) {
  __shared__ int hs[256], hd[256];
  int t = threadIdx.x, b = blockIdx.x;
  hs[t] = bhS[b * 256 + t] + c_base_s[t];
  hd[t] = bhD[b * 256 + t] + c_base_d[t];
  __syncthreads();
  int base = b * 4096;
  #pragma unroll
  for (int k = 0; k < 4; k++) {
    int i = base + 4 * t + 1024 * k;
    if (i + 3 < e) {
      int4 s4 = *(const int4*)&src[i];
      int4 d4 = *(const int4*)&dst[i];
      int sv[4] = {s4.x, s4.y, s4.z, s4.w};
      int dv[4] = {d4.x, d4.y, d4.z, d4.w};
      #pragma unroll
      for (int j = 0; j < 4; j++) {
        int ps = atomicAdd(&hs[sv[j] >> 9], 1);
        srcbuf[ps] = sv[j];
        int pd = atomicAdd(&hd[dv[j] >> 9], 1);
        edges1[pd] = ((unsigned)sv[j] << 9) | (unsigned)(dv[j] & 511);
      }
    } else {
      for (int j = i; j < e && j < i + 4; j++) {
        int s = src[j], d = dst[j];
        int ps = atomicAdd(&hs[s >> 9], 1);
        srcbuf[ps] = s;
        int pd = atomicAdd(&hd[d >> 9], 1);
        edges1[pd] = ((unsigned)s << 9) | (unsigned)(d & 511);
      }
    }
  }
}

// ---------------- out-degree + pre-scaled bf16 cast (block owns nodes [b*512, b*512+512)) -------
__global__ __launch_bounds__(256) void degout_cast(
    const int* __restrict__ srcbuf, const int* __restrict__ c_base_s,
    const float* __restrict__ node_feat, float* __restrict__ inv_out,
    unsigned short* __restrict__ xb, int n) {
  __shared__ int hist[512];
  __shared__ float sInv[512];
  int b = blockIdx.x, t = threadIdx.x;
  hist[t] = 0; hist[t + 256] = 0;
  __syncthreads();
  int s = c_base_s[b], e = c_base_s[b + 1];
  for (int i = s + t; i < e; i += TPB) atomicAdd(&hist[srcbuf[i] & 511], 1);
  __syncthreads();
  int rstart = b << 9;
  int nrows = min(512, n - rstart);
  #pragma unroll
  for (int k = 0; k < 2; k++) {
    int r = t + k * 256;
    if (r < nrows) {
      float iv = rsqrtf(fmaxf((float)hist[r], 1.0f));
      sInv[r] = iv;
      inv_out[rstart + r] = iv;
    }
  }
  __syncthreads();
  int total4 = nrows * 16;                  // 64 feats = 16 float4 per row
  const float* xbase = node_feat + (size_t)rstart * 64;
  unsigned short* obase = xb + (size_t)rstart * 64;
  for (int u = t; u < total4; u += TPB) {
    int r = u >> 4;
    float sc = sInv[r];
    float4 v = *(const float4*)&xbase[(size_t)u * 4];
    ushort4 o;
    o.x = f2bf(v.x * sc); o.y = f2bf(v.y * sc);
    o.z = f2bf(v.z * sc); o.w = f2bf(v.w * sc);
    *(ushort4*)&obase[(size_t)u * 4] = o;
  }
}

// ---------------- fine sort by dst + row_ptr + inv_in ----------------
__global__ __launch_bounds__(256) void scatter2(
    const unsigned* __restrict__ edges1, const int* __restrict__ c_base_d,
    int* __restrict__ row_ptr, float* __restrict__ inv_in,
    int* __restrict__ col, int n) {
  __shared__ int sOut[CAP_S2];
  __shared__ int hist[512];
  __shared__ int cur[512];
  __shared__ int psum[256];
  int b = blockIdx.x, t = threadIdx.x;
  int s = c_base_d[b], e = c_base_d[b + 1];
  int rstart = b << 9;
  int nrows = min(512, n - rstart);
  hist[t] = 0; hist[t + 256] = 0;
  __syncthreads();
  for (int i = s + t; i < e; i += TPB) atomicAdd(&hist[edges1[i] & 511u], 1);
  __syncthreads();
  int h0 = hist[2 * t], h1 = hist[2 * t + 1];
  psum[t] = h0 + h1; __syncthreads();
  for (int off = 1; off < 256; off <<= 1) {
    int a = (t >= off) ? psum[t - off] : 0;
    __syncthreads(); psum[t] += a; __syncthreads();
  }
  int ex = psum[t] - (h0 + h1);
  cur[2 * t] = ex; cur[2 * t + 1] = ex + h0;
  if (2 * t < nrows) {
    row_ptr[rstart + 2 * t] = s + ex;
    inv_in[rstart + 2 * t] = rsqrtf(fmaxf((float)h0, 1.0f));
  }
  if (2 * t + 1 < nrows) {
    row_ptr[rstart + 2 * t + 1] = s + ex + h0;
    inv_in[rstart + 2 * t + 1] = rsqrtf(fmaxf((float)h1, 1.0f));
  }
  __syncthreads();
  for (int i = s + t; i < e; i += TPB) {
    unsigned v = edges1[i];
    int pos = atomicAdd(&cur[v & 511u], 1);
    int sv = (int)(v >> 9);
    if (pos < CAP_S2) sOut[pos] = sv;
    else col[s + pos] = sv;   // statistically never; correctness fallback
  }
  __syncthreads();
  int m = min(e - s, CAP_S2);
  for (int k = t; k < m; k += TPB) col[s + k] = sOut[k];
}

// ---------------- SpMM: 1 wave/row, 8 lanes x uint4, 32 edges in flight (clamped+masked) --------
__global__ __launch_bounds__(256) void spmm_bf16(
    const unsigned short* __restrict__ xb,
    const int* __restrict__ row_ptr, const int* __restrict__ col,
    float* __restrict__ agg, int n) {
  int wid = (blockIdx.x * TPB + threadIdx.x) >> 6;
  if (wid >= n) return;
  int lane = threadIdx.x & 63;
  int g = lane >> 3;            // edge group 0..7
  int l8 = (lane & 7) << 3;     // feature offset (8 feats = 16 B)
  int s = row_ptr[wid], e = row_ptr[wid + 1];
  float a0 = 0, a1 = 0, a2 = 0, a3 = 0, a4 = 0, a5 = 0, a6 = 0, a7 = 0;
  for (int i = s + g; i < e; i += 32) {   // 32 edges in flight per wave, one round for deg<=32
    int ec = e - 1;
    int i1 = i + 8, i2 = i + 16, i3 = i + 24;
    int c0 = col[i];
    int c1 = col[min(i1, ec)];
    int c2 = col[min(i2, ec)];
    int c3 = col[min(i3, ec)];
    float m1 = (i1 < e) ? 1.f : 0.f;
    float m2 = (i2 < e) ? 1.f : 0.f;
    float m3 = (i3 < e) ? 1.f : 0.f;
    uint4 r0 = *(const uint4*)&xb[(size_t)c0 * 64 + l8];
    uint4 r1 = *(const uint4*)&xb[(size_t)c1 * 64 + l8];
    uint4 r2 = *(const uint4*)&xb[(size_t)c2 * 64 + l8];
    uint4 r3 = *(const uint4*)&xb[(size_t)c3 * 64 + l8];
    a0 += bflo(r0.x); a1 += bfhi(r0.x); a2 += bflo(r0.y); a3 += bfhi(r0.y);
    a4 += bflo(r0.z); a5 += bfhi(r0.z); a6 += bflo(r0.w); a7 += bfhi(r0.w);
    a0 = fmaf(m1, bflo(r1.x), a0); a1 = fmaf(m1, bfhi(r1.x), a1);
    a2 = fmaf(m1, bflo(r1.y), a2); a3 = fmaf(m1, bfhi(r1.y), a3);
    a4 = fmaf(m1, bflo(r1.z), a4); a5 = fmaf(m1, bfhi(r1.z), a5);
    a6 = fmaf(m1, bflo(r1.w), a6); a7 = fmaf(m1, bfhi(r1.w), a7);
    a0 = fmaf(m2, bflo(r2.x), a0); a1 = fmaf(m2, bfhi(r2.x), a1);
    a2 = fmaf(m2, bflo(r2.y), a2); a3 = fmaf(m2, bfhi(r2.y), a3);
    a4 = fmaf(m2, bflo(r2.z), a4); a5 = fmaf(m2, bfhi(r2.z), a5);
    a6 = fmaf(m2, bflo(r2.w), a6); a7 = fmaf(m2, bfhi(r2.w), a7);
    a0 = fmaf(m3, bflo(r3.x), a0); a1 = fmaf(m3, bfhi(r3.x), a1);
    a2 = fmaf(m3, bflo(r3.y), a2); a3 = fmaf(m3, bfhi(r3.y), a3);
    a4 = fmaf(m3, bflo(r3.z), a4); a5 = fmaf(m3, bfhi(r3.z), a5);
    a6 = fmaf(m3, bflo(r3.w), a6); a7 = fmaf(m3, bfhi(r3.w), a7);
  }
  a0 += __shfl_xor(a0, 8); a0 += __shfl_xor(a0, 16); a0 += __shfl_xor(a0, 32);
  a1 += __shfl_xor(a1, 8); a1 += __shfl_xor(a1, 16); a1 += __shfl_xor(a1, 32);
  a2 += __shfl_xor(a2, 8); a2 += __shfl_xor(a2, 16); a2 += __shfl_xor(a2, 32);
  a3 += __shfl_xor(a3, 8); a3 += __shfl_xor(a3, 16); a3 += __shfl_xor(a3, 32);
  a4 += __shfl_xor(a4, 8); a4 += __shfl_xor(a4, 16); a4 += __shfl_xor(a4, 32);
  a5 += __shfl_xor(a5, 8); a5 += __shfl_xor(a5, 16); a5 += __shfl_xor(a5, 32);
  a6 += __shfl_xor(a6, 8); a6 += __shfl_xor(a6, 16); a6 += __shfl_xor(a6, 32);
  a7 += __shfl_xor(a7, 8); a7 += __shfl_xor(a7, 16); a7 += __shfl_xor(a7, 32);
  if (g == 0) {
    float4 lo = {a0, a1, a2, a3};
    float4 hi = {a4, a5, a6, a7};
    *(float4*)&agg[(size_t)wid * 64 + l8] = lo;
    *(float4*)&agg[(size_t)wid * 64 + l8 + 4] = hi;
  }
}

// ---------------- GEMM + bias + ReLU + pool + (optional) next-layer bf16 copy ----------------
__global__ __launch_bounds__(256) void gemm_relu_pool(
    const float* __restrict__ agg, const float* __restrict__ inv_in,
    const float* __restrict__ inv_out,
    const float* __restrict__ W, const float* __restrict__ bias,
    float* __restrict__ out_cat, float* __restrict__ out_pool,
    unsigned short* __restrict__ xb_next, int n) {
  __shared__ float sW[64 * 64];
  __shared__ float sXT[64][68];
  int t = threadIdx.x;
  int row0 = blockIdx.x * 64;
  for (int i4 = t * 4; i4 < 4096; i4 += 1024)
    *(float4*)&sW[i4] = *(const float4*)&W[i4];
  for (int i = t; i < 4096; i += TPB) {
    int r = i >> 6, f = i & 63;
    int row = row0 + r;
    sXT[f][r] = (row < n) ? agg[(size_t)row * 64 + f] * inv_in[row] : 0.f;
  }
  __syncthreads();
  int tj = t & 15, tr = t >> 4;
  int j4 = tj << 2, r4 = tr << 2;
  const float4 bv = *(const float4*)&bias[j4];
  float4 a0 = bv, a1 = bv, a2 = bv, a3 = bv;
  #pragma unroll 8
  for (int f = 0; f < 64; f++) {
    float4 w  = *(const float4*)&sW[f * 64 + j4];
    float4 xv = *(const float4*)&sXT[f][r4];
    a0.x = fmaf(xv.x, w.x, a0.x); a0.y = fmaf(xv.x, w.y, a0.y);
    a0.z = fmaf(xv.x, w.z, a0.z); a0.w = fmaf(xv.x, w.w, a0.w);
    a1.x = fmaf(xv.y, w.x, a1.x); a1.y = fmaf(xv.y, w.y, a1.y);
    a1.z = fmaf(xv.y, w.z, a1.z); a1.w = fmaf(xv.y, w.w, a1.w);
    a2.x = fmaf(xv.z, w.x, a2.x); a2.y = fmaf(xv.z, w.y, a2.y);
    a2.z = fmaf(xv.z, w.z, a2.z); a2.w = fmaf(xv.z, w.w, a2.w);
    a3.x = fmaf(xv.w, w.x, a3.x); a3.y = fmaf(xv.w, w.y, a3.y);
    a3.z = fmaf(xv.w, w.z, a3.z); a3.w = fmaf(xv.w, w.w, a3.w);
  }
  float4 accs[4] = {a0, a1, a2, a3};
  #pragma unroll
  for (int ri = 0; ri < 4; ri++) {
    int row = row0 + r4 + ri;
    if (row < n) {
      float4 h = accs[ri];
      h.x = fmaxf(h.x, 0.f); h.y = fmaxf(h.y, 0.f);
      h.z = fmaxf(h.z, 0.f); h.w = fmaxf(h.w, 0.f);
      *(float4*)&out_cat[(size_t)row * 192 + j4] = h;
      if (xb_next) {
        float sc = inv_out[row];
        ushort4 o;
        o.x = f2bf(h.x * sc); o.y = f2bf(h.y * sc);
        o.z = f2bf(h.z * sc); o.w = f2bf(h.w * sc);
        *(ushort4*)&xb_next[(size_t)row * 64 + j4] = o;
      }
      float part = h.x + h.y + h.z + h.w;
      part += __shfl_xor(part, 1);
      part += __shfl_xor(part, 2);
      part += __shfl_xor(part, 4);
      part += __shfl_xor(part, 8);
      if (tj == 0) out_pool[row] = part;
    }
  }
}

// ---------------- launch ----------------

extern "C" void kernel_launch(void* const* d_in, const int* in_sizes, int n_in,
                              void* d_out, int out_size, void* d_ws, size_t ws_size,
                              hipStream_t stream) {
  const float* node_feat = (const float*)d_in[0];
  const int* src = (const int*)d_in[1];
  const int* dst = (const int*)d_in[2];
  const float* Ws[3] = {(const float*)d_in[4], (const float*)d_in[6], (const float*)d_in[8]};
  const float* bs[3] = {(const float*)d_in[5], (const float*)d_in[7], (const float*)d_in[9]};
  float* out = (float*)d_out;
  int n = in_sizes[0] / 64;
  int e = in_sizes[1];
  int nbb = (n + 511) >> 9;         // coarse buckets (196 for n=100k)
  int nblk = (e + 4095) / 4096;     // edge blocks (391)

  char* p = (char*)d_ws;
  float* agg = (float*)p;       p += (size_t)n * 64 * sizeof(float);
  unsigned short* xb = (unsigned short*)p; p += (size_t)n * 64 * sizeof(unsigned short);
  float* inv_out = (float*)p;   p += (size_t)n * sizeof(float);
  float* inv_in = (float*)p;    p += (size_t)n * sizeof(float);
  int* row_ptr = (int*)p;       p += ((size_t)n + 4) * sizeof(int);
  int* c_base_s = (int*)p;      p += 260 * sizeof(int);
  int* c_base_d = (int*)p;      p += 260 * sizeof(int);
  int* csum = (int*)p;          p += 512 * sizeof(int);
  int* bhS = (int*)p;           p += (size_t)nblk * 256 * sizeof(int);
  int* bhD = (int*)p;           p += (size_t)nblk * 256 * sizeof(int);
  unsigned* edges1 = (unsigned*)p; p += (size_t)e * sizeof(unsigned);
  int* col = (int*)p;           p += (size_t)e * sizeof(int);
  int* srcbuf = col;            // alias: degout_cast consumes srcbuf before scatter2 writes col

  coarse_hist<<<nblk, TPB, 0, stream>>>(src, dst, e, bhS, bhD);
  scan_buckets<<<512, TPB, 0, stream>>>(bhS, bhD, nblk, csum);
  scan_bases<<<1, TPB, 0, stream>>>(csum, c_base_s, c_base_d, row_ptr, n, e);
  scatter_both<<<nblk, TPB, 0, stream>>>(src, dst, e, bhS, bhD, c_base_s, c_base_d,
                                         srcbuf, edges1);
  degout_cast<<<nbb, TPB, 0, stream>>>(srcbuf, c_base_s, node_feat, inv_out, xb, n);
  scatter2<<<nbb, TPB, 0, stream>>>(edges1, c_base_d, row_ptr, inv_in, col, n);

  float* cat_base = out + (size_t)3 * n;
  for (int layer = 0; layer < 3; layer++) {
    spmm_bf16<<<(n + 3) / 4, TPB, 0, stream>>>(xb, row_ptr, col, agg, n);
    gemm_relu_pool<<<(n + 63) / 64, TPB, 0, stream>>>(agg, inv_in, inv_out, Ws[layer], bs[layer],
        cat_base + (size_t)layer * 64, out + (size_t)layer * n,
        (layer < 2) ? xb : (unsigned short*)nullptr, n);
  }
}

// Round 8
// 353.449 us; speedup vs baseline: 5.5562x; 1.0232x over previous
//
#include <hip/hip_runtime.h>

// GCN: n=100k nodes, E=1.6M edges, D=64, 3 layers.
// Round 8: no histogram/scan chain. Coarse buckets are over-allocated fixed slots
// (CAPB=16384 >> mean 8192, sigma ~90); scatter_both reserves ranges via one global
// atomicAdd per (block,bucket). Sort+degout+cast fused into one 196-block kernel.
// spmm uses explicit row_beg/row_end (buckets are gapped).
// Packing (src<<9)|(dst&511) needs n <= 2^17.

#define TPB 256
#define CAPB 16384     // per-bucket slot capacity (92 sigma above mean)
#define CAP_S2 10240   // LDS staging for sorted col; bucket count ~8.2k avg

__device__ __forceinline__ unsigned short f2bf(float f) {   // RNE fp32->bf16
  unsigned u = __float_as_uint(f);
  u += 0x7fff + ((u >> 16) & 1);
  return (unsigned short)(u >> 16);
}
__device__ __forceinline__ float bflo(unsigned u) { return __uint_as_float(u << 16); }
__device__ __forceinline__ float bfhi(unsigned u) { return __uint_as_float(u & 0xffff0000u); }

// ---------------- cursor init: cur[b] = b*CAPB ----------------
__global__ void init_cursors(int* __restrict__ cur_s, int* __restrict__ cur_d) {
  int t = threadIdx.x;
  cur_s[t] = t * CAPB;
  cur_d[t] = t * CAPB;
}

// ---------------- one read pass, two coarse scatters (LDS count -> global reserve) -------------
__global__ __launch_bounds__(256) void scatter_both(
    const int* __restrict__ src, const int* __restrict__ dst, int e,
    int* __restrict__ cur_s, int* __restrict__ cur_d,
    int* __restrict__ srcbuf, unsigned* __restrict__ edges1) {
  __shared__ int hs[256], hd[256];
  int t = threadIdx.x, b = blockIdx.x;
  hs[t] = 0; hd[t] = 0;
  __syncthreads();
  int base = b * 4096;
  int sv[16], dv[16];
  #pragma unroll
  for (int k = 0; k < 4; k++) {
    int i = base + 4 * t + 1024 * k;
    if (i + 3 < e) {
      int4 s4 = *(const int4*)&src[i];
      int4 d4 = *(const int4*)&dst[i];
      sv[4*k] = s4.x; sv[4*k+1] = s4.y; sv[4*k+2] = s4.z; sv[4*k+3] = s4.w;
      dv[4*k] = d4.x; dv[4*k+1] = d4.y; dv[4*k+2] = d4.z; dv[4*k+3] = d4.w;
    } else {
      #pragma unroll
      for (int j = 0; j < 4; j++) {
        int idx = i + j;
        if (idx < e) { sv[4*k+j] = src[idx]; dv[4*k+j] = dst[idx]; }
        else { sv[4*k+j] = -1; dv[4*k+j] = -1; }
      }
    }
  }
  #pragma unroll
  for (int k = 0; k < 16; k++) {
    if (dv[k] >= 0) {
      atomicAdd(&hs[sv[k] >> 9], 1);
      atomicAdd(&hd[dv[k] >> 9], 1);
    }
  }
  __syncthreads();
  int bs = hs[t], bd = hd[t];
  hs[t] = bs ? atomicAdd(&cur_s[t], bs) : 0;
  hd[t] = bd ? atomicAdd(&cur_d[t], bd) : 0;
  __syncthreads();
  #pragma unroll
  for (int k = 0; k < 16; k++) {
    if (dv[k] >= 0) {
      int ps = atomicAdd(&hs[sv[k] >> 9], 1);
      srcbuf[ps] = sv[k];
      int pd = atomicAdd(&hd[dv[k] >> 9], 1);
      edges1[pd] = ((unsigned)sv[k] << 9) | (unsigned)(dv[k] & 511);
    }
  }
}

// ---------------- fused: dst fine-sort (row_beg/row_end/inv_in/col) + out-degree + bf16 cast ----
// block b owns nodes [b*512, b*512+512), src slot [b*CAPB, cur_s[b]), dst slot [b*CAPB, cur_d[b))
__global__ __launch_bounds__(256) void sort_deg_cast(
    const unsigned* __restrict__ edges1, const int* __restrict__ srcbuf,
    const int* __restrict__ cur_s, const int* __restrict__ cur_d,
    const float* __restrict__ node_feat,
    int* __restrict__ row_beg, int* __restrict__ row_end,
    float* __restrict__ inv_in, float* __restrict__ inv_out,
    unsigned short* __restrict__ xb, int* __restrict__ col, int n) {
  __shared__ int sOut[CAP_S2];
  __shared__ int hist[512], cur[512];
  __shared__ int psum[256];
  __shared__ int dhist[512];
  __shared__ float sInv[512];
  int b = blockIdx.x, t = threadIdx.x;
  int sbase = b * CAPB;
  int es = cur_s[b];                  // end of this block's src slot
  int ed = cur_d[b];                  // end of this block's dst slot
  int rstart = b << 9;
  int nrows = min(512, n - rstart);
  hist[t] = 0; hist[t + 256] = 0;
  dhist[t] = 0; dhist[t + 256] = 0;
  __syncthreads();
  for (int i = sbase + t; i < ed; i += TPB) atomicAdd(&hist[edges1[i] & 511u], 1);
  for (int i = sbase + t; i < es; i += TPB) atomicAdd(&dhist[srcbuf[i] & 511], 1);
  __syncthreads();
  // out-degree -> inv_out + LDS copy for the cast below
  #pragma unroll
  for (int k = 0; k < 2; k++) {
    int r = t + k * 256;
    if (r < nrows) {
      float iv = rsqrtf(fmaxf((float)dhist[r], 1.0f));
      sInv[r] = iv;
      inv_out[rstart + r] = iv;
    }
  }
  // in-degree scan -> row_beg/row_end/inv_in + place cursors
  int h0 = hist[2 * t], h1 = hist[2 * t + 1];
  psum[t] = h0 + h1; __syncthreads();
  for (int off = 1; off < 256; off <<= 1) {
    int a = (t >= off) ? psum[t - off] : 0;
    __syncthreads(); psum[t] += a; __syncthreads();
  }
  int ex = psum[t] - (h0 + h1);
  cur[2 * t] = ex; cur[2 * t + 1] = ex + h0;
  if (2 * t < nrows) {
    row_beg[rstart + 2 * t] = sbase + ex;
    row_end[rstart + 2 * t] = sbase + ex + h0;
    inv_in[rstart + 2 * t] = rsqrtf(fmaxf((float)h0, 1.0f));
  }
  if (2 * t + 1 < nrows) {
    row_beg[rstart + 2 * t + 1] = sbase + ex + h0;
    row_end[rstart + 2 * t + 1] = sbase + ex + h0 + h1;
    inv_in[rstart + 2 * t + 1] = rsqrtf(fmaxf((float)h1, 1.0f));
  }
  __syncthreads();
  for (int i = sbase + t; i < ed; i += TPB) {
    unsigned v = edges1[i];
    int pos = atomicAdd(&cur[v & 511u], 1);
    int svv = (int)(v >> 9);
    if (pos < CAP_S2) sOut[pos] = svv;
    else col[sbase + pos] = svv;      // statistically never; correctness fallback
  }
  __syncthreads();
  int m = min(ed - sbase, CAP_S2);
  for (int k = t; k < m; k += TPB) col[sbase + k] = sOut[k];
  // pre-scaled bf16 cast of this block's feature rows (sInv valid since the scan barriers)
  int total4 = nrows * 16;            // 64 feats = 16 float4 per row
  const float* xbase = node_feat + (size_t)rstart * 64;
  unsigned short* obase = xb + (size_t)rstart * 64;
  for (int u = t; u < total4; u += TPB) {
    int r = u >> 4;
    float sc = sInv[r];
    float4 v = *(const float4*)&xbase[(size_t)u * 4];
    ushort4 o;
    o.x = f2bf(v.x * sc); o.y = f2bf(v.y * sc);
    o.z = f2bf(v.z * sc); o.w = f2bf(v.w * sc);
    *(ushort4*)&obase[(size_t)u * 4] = o;
  }
}

// ---------------- SpMM: 1 wave/row, 8 lanes x uint4, 32 edges in flight (clamped+masked) --------
__global__ __launch_bounds__(256) void spmm_bf16(
    const unsigned short* __restrict__ xb,
    const int* __restrict__ row_beg, const int* __restrict__ row_end,
    const int* __restrict__ col,
    float* __restrict__ agg, int n) {
  int wid = (blockIdx.x * TPB + threadIdx.x) >> 6;
  if (wid >= n) return;
  int lane = threadIdx.x & 63;
  int g = lane >> 3;            // edge group 0..7
  int l8 = (lane & 7) << 3;     // feature offset (8 feats = 16 B)
  int s = row_beg[wid], e = row_end[wid];
  float a0 = 0, a1 = 0, a2 = 0, a3 = 0, a4 = 0, a5 = 0, a6 = 0, a7 = 0;
  for (int i = s + g; i < e; i += 32) {   // 32 edges in flight per wave
    int ec = e - 1;
    int i1 = i + 8, i2 = i + 16, i3 = i + 24;
    int c0 = col[i];
    int c1 = col[min(i1, ec)];
    int c2 = col[min(i2, ec)];
    int c3 = col[min(i3, ec)];
    float m1 = (i1 < e) ? 1.f : 0.f;
    float m2 = (i2 < e) ? 1.f : 0.f;
    float m3 = (i3 < e) ? 1.f : 0.f;
    uint4 r0 = *(const uint4*)&xb[(size_t)c0 * 64 + l8];
    uint4 r1 = *(const uint4*)&xb[(size_t)c1 * 64 + l8];
    uint4 r2 = *(const uint4*)&xb[(size_t)c2 * 64 + l8];
    uint4 r3 = *(const uint4*)&xb[(size_t)c3 * 64 + l8];
    a0 += bflo(r0.x); a1 += bfhi(r0.x); a2 += bflo(r0.y); a3 += bfhi(r0.y);
    a4 += bflo(r0.z); a5 += bfhi(r0.z); a6 += bflo(r0.w); a7 += bfhi(r0.w);
    a0 = fmaf(m1, bflo(r1.x), a0); a1 = fmaf(m1, bfhi(r1.x), a1);
    a2 = fmaf(m1, bflo(r1.y), a2); a3 = fmaf(m1, bfhi(r1.y), a3);
    a4 = fmaf(m1, bflo(r1.z), a4); a5 = fmaf(m1, bfhi(r1.z), a5);
    a6 = fmaf(m1, bflo(r1.w), a6); a7 = fmaf(m1, bfhi(r1.w), a7);
    a0 = fmaf(m2, bflo(r2.x), a0); a1 = fmaf(m2, bfhi(r2.x), a1);
    a2 = fmaf(m2, bflo(r2.y), a2); a3 = fmaf(m2, bfhi(r2.y), a3);
    a4 = fmaf(m2, bflo(r2.z), a4); a5 = fmaf(m2, bfhi(r2.z), a5);
    a6 = fmaf(m2, bflo(r2.w), a6); a7 = fmaf(m2, bfhi(r2.w), a7);
    a0 = fmaf(m3, bflo(r3.x), a0); a1 = fmaf(m3, bfhi(r3.x), a1);
    a2 = fmaf(m3, bflo(r3.y), a2); a3 = fmaf(m3, bfhi(r3.y), a3);
    a4 = fmaf(m3, bflo(r3.z), a4); a5 = fmaf(m3, bfhi(r3.z), a5);
    a6 = fmaf(m3, bflo(r3.w), a6); a7 = fmaf(m3, bfhi(r3.w), a7);
  }
  a0 += __shfl_xor(a0, 8); a0 += __shfl_xor(a0, 16); a0 += __shfl_xor(a0, 32);
  a1 += __shfl_xor(a1, 8); a1 += __shfl_xor(a1, 16); a1 += __shfl_xor(a1, 32);
  a2 += __shfl_xor(a2, 8); a2 += __shfl_xor(a2, 16); a2 += __shfl_xor(a2, 32);
  a3 += __shfl_xor(a3, 8); a3 += __shfl_xor(a3, 16); a3 += __shfl_xor(a3, 32);
  a4 += __shfl_xor(a4, 8); a4 += __shfl_xor(a4, 16); a4 += __shfl_xor(a4, 32);
  a5 += __shfl_xor(a5, 8); a5 += __shfl_xor(a5, 16); a5 += __shfl_xor(a5, 32);
  a6 += __shfl_xor(a6, 8); a6 += __shfl_xor(a6, 16); a6 += __shfl_xor(a6, 32);
  a7 += __shfl_xor(a7, 8); a7 += __shfl_xor(a7, 16); a7 += __shfl_xor(a7, 32);
  if (g == 0) {
    float4 lo = {a0, a1, a2, a3};
    float4 hi = {a4, a5, a6, a7};
    *(float4*)&agg[(size_t)wid * 64 + l8] = lo;
    *(float4*)&agg[(size_t)wid * 64 + l8 + 4] = hi;
  }
}

// ---------------- GEMM + bias + ReLU + pool + (optional) next-layer bf16 copy ----------------
__global__ __launch_bounds__(256) void gemm_relu_pool(
    const float* __restrict__ agg, const float* __restrict__ inv_in,
    const float* __restrict__ inv_out,
    const float* __restrict__ W, const float* __restrict__ bias,
    float* __restrict__ out_cat, float* __restrict__ out_pool,
    unsigned short* __restrict__ xb_next, int n) {
  __shared__ float sW[64 * 64];
  __shared__ float sXT[64][68];
  int t = threadIdx.x;
  int row0 = blockIdx.x * 64;
  for (int i4 = t * 4; i4 < 4096; i4 += 1024)
    *(float4*)&sW[i4] = *(const float4*)&W[i4];
  for (int i = t; i < 4096; i += TPB) {
    int r = i >> 6, f = i & 63;
    int row = row0 + r;
    sXT[f][r] = (row < n) ? agg[(size_t)row * 64 + f] * inv_in[row] : 0.f;
  }
  __syncthreads();
  int tj = t & 15, tr = t >> 4;
  int j4 = tj << 2, r4 = tr << 2;
  const float4 bv = *(const float4*)&bias[j4];
  float4 a0 = bv, a1 = bv, a2 = bv, a3 = bv;
  #pragma unroll 8
  for (int f = 0; f < 64; f++) {
    float4 w  = *(const float4*)&sW[f * 64 + j4];
    float4 xv = *(const float4*)&sXT[f][r4];
    a0.x = fmaf(xv.x, w.x, a0.x); a0.y = fmaf(xv.x, w.y, a0.y);
    a0.z = fmaf(xv.x, w.z, a0.z); a0.w = fmaf(xv.x, w.w, a0.w);
    a1.x = fmaf(xv.y, w.x, a1.x); a1.y = fmaf(xv.y, w.y, a1.y);
    a1.z = fmaf(xv.y, w.z, a1.z); a1.w = fmaf(xv.y, w.w, a1.w);
    a2.x = fmaf(xv.z, w.x, a2.x); a2.y = fmaf(xv.z, w.y, a2.y);
    a2.z = fmaf(xv.z, w.z, a2.z); a2.w = fmaf(xv.z, w.w, a2.w);
    a3.x = fmaf(xv.w, w.x, a3.x); a3.y = fmaf(xv.w, w.y, a3.y);
    a3.z = fmaf(xv.w, w.z, a3.z); a3.w = fmaf(xv.w, w.w, a3.w);
  }
  float4 accs[4] = {a0, a1, a2, a3};
  #pragma unroll
  for (int ri = 0; ri < 4; ri++) {
    int row = row0 + r4 + ri;
    if (row < n) {
      float4 h = accs[ri];
      h.x = fmaxf(h.x, 0.f); h.y = fmaxf(h.y, 0.f);
      h.z = fmaxf(h.z, 0.f); h.w = fmaxf(h.w, 0.f);
      *(float4*)&out_cat[(size_t)row * 192 + j4] = h;
      if (xb_next) {
        float sc = inv_out[row];
        ushort4 o;
        o.x = f2bf(h.x * sc); o.y = f2bf(h.y * sc);
        o.z = f2bf(h.z * sc); o.w = f2bf(h.w * sc);
        *(ushort4*)&xb_next[(size_t)row * 64 + j4] = o;
      }
      float part = h.x + h.y + h.z + h.w;
      part += __shfl_xor(part, 1);
      part += __shfl_xor(part, 2);
      part += __shfl_xor(part, 4);
      part += __shfl_xor(part, 8);
      if (tj == 0) out_pool[row] = part;
    }
  }
}

// ---------------- launch ----------------

extern "C" void kernel_launch(void* const* d_in, const int* in_sizes, int n_in,
                              void* d_out, int out_size, void* d_ws, size_t ws_size,
                              hipStream_t stream) {
  const float* node_feat = (const float*)d_in[0];
  const int* src = (const int*)d_in[1];
  const int* dst = (const int*)d_in[2];
  const float* Ws[3] = {(const float*)d_in[4], (const float*)d_in[6], (const float*)d_in[8]};
  const float* bs[3] = {(const float*)d_in[5], (const float*)d_in[7], (const float*)d_in[9]};
  float* out = (float*)d_out;
  int n = in_sizes[0] / 64;
  int e = in_sizes[1];
  int nbb = (n + 511) >> 9;         // coarse buckets (196 for n=100k)
  int nblk = (e + 4095) / 4096;     // edge blocks (391)
  size_t slots = (size_t)nbb * CAPB;

  char* p = (char*)d_ws;
  float* agg = (float*)p;       p += (size_t)n * 64 * sizeof(float);
  unsigned short* xb = (unsigned short*)p; p += (size_t)n * 64 * sizeof(unsigned short);
  float* inv_out = (float*)p;   p += (size_t)n * sizeof(float);
  float* inv_in = (float*)p;    p += (size_t)n * sizeof(float);
  int* row_beg = (int*)p;       p += (size_t)n * sizeof(int);
  int* row_end = (int*)p;       p += (size_t)n * sizeof(int);
  int* cur_s = (int*)p;         p += 256 * sizeof(int);
  int* cur_d = (int*)p;         p += 256 * sizeof(int);
  unsigned* edges1 = (unsigned*)p; p += slots * sizeof(unsigned);
  int* srcbuf = (int*)p;        p += slots * sizeof(int);
  int* col = (int*)p;           p += slots * sizeof(int);

  init_cursors<<<1, 256, 0, stream>>>(cur_s, cur_d);
  scatter_both<<<nblk, TPB, 0, stream>>>(src, dst, e, cur_s, cur_d, srcbuf, edges1);
  sort_deg_cast<<<nbb, TPB, 0, stream>>>(edges1, srcbuf, cur_s, cur_d, node_feat,
                                         row_beg, row_end, inv_in, inv_out, xb, col, n);

  float* cat_base = out + (size_t)3 * n;
  for (int layer = 0; layer < 3; layer++) {
    spmm_bf16<<<(n + 3) / 4, TPB, 0, stream>>>(xb, row_beg, row_end, col, agg, n);
    gemm_relu_pool<<<(n + 63) / 64, TPB, 0, stream>>>(agg, inv_in, inv_out, Ws[layer], bs[layer],
        cat_base + (size_t)layer * 64, out + (size_t)layer * n,
        (layer < 2) ? xb : (unsigned short*)nullptr, n);
  }
}